// Round 6
// baseline (2039.134 us; speedup 1.0000x reference)
//
#include <hip/hip_runtime.h>
#include <cstdint>

// ---------------------------------------------------------------------------
// JukeboxAutoEncoder fp32, round 13.
// r12 post-mortem: removing s_loads from the loop raised VALUBusy 55->72%
//   (mechanism confirmed) but the co-lane port added unpack VALU + cost
//   occupancy -> net loss. up reverted to r10 (66us known).
// conv3 v2 (this round's change): weights -> LDS, co split across blockIdx.z.
//   Block = 128 t x 32 co; ws = 3*64*32 floats (24KB) staged once; x tile
//   36KB; 60KB total -> 2 blocks/CU (16 waves). Inner loop per ci:
//   3 broadcast ds_read_b128 (weights) + 4 ds_read_b64 (x) + 24 FMA -> zero
//   s_load in loop, precise lgkmcnt, DS 22cyc < VALU 48cyc.
// Output layout (flat f32): x_hat[262144] | loss_vq[1] | ids[32768] | sim[16777216]
// ---------------------------------------------------------------------------

#define OFF_LOSS 262144
#define OFF_IDS  262145
#define OFF_SIM  294913

// ---------------- down0: (B,65536,1) -> (B,32768,64), K=4 stride2, relu ----
__global__ __launch_bounds__(256) void down0_kernel(
    const float* __restrict__ x, const float* __restrict__ w,
    const float* __restrict__ bias, float* __restrict__ y)
{
  int idx = blockIdx.x * 256 + threadIdx.x;   // enumerates (b, t, co)
  int co = idx & 63;
  int r  = idx >> 6;
  int t  = r & 32767;
  int b  = r >> 15;
  const float* xb = x + (size_t)b * 65536;
  float acc = bias[co];
  #pragma unroll
  for (int k = 0; k < 4; ++k) {
    int gt = 2 * t - 1 + k;
    float xv = ((unsigned)gt < 65536u) ? xb[gt] : 0.f;
    acc += xv * w[k * 64 + co];
  }
  y[(size_t)idx] = fmaxf(acc, 0.f);
}

// ---------------- conv3 v2: K=3, dil DIL, 64->64, relu, optional +res -----
// grid (T/128, B, 2). Block: 128 t x 32 co (z picks co half). 512 thr =
// 8 waves; wave wv owns co0 = z*32 + wv*4; lane covers t = t0 + 2*lane + i.
// Weights in LDS (staged once, zero s_load in loop).
template <int DIL, bool HAS_RES>
__global__ __launch_bounds__(512, 4) void conv3_kernel(
    const float* __restrict__ x, const float* __restrict__ w,
    const float* __restrict__ bias, const float* res,
    float* y, int T)
{
  constexpr int TT  = 128;
  constexpr int XT  = TT + 2 * DIL;
  constexpr int XS  = 144;                   // swizzle-safe row stride
  constexpr int NV  = 2 + 2 * DIL;
  __shared__ float xs[64 * XS];              // 36 KB
  __shared__ float ws[3 * 64 * 32];          // 24 KB
  const int tid  = threadIdx.x;
  const int lane = tid & 63;
  const int b    = blockIdx.y;
  const int z    = blockIdx.z;
  const int t0   = blockIdx.x * TT;
  const int wv   = __builtin_amdgcn_readfirstlane(tid >> 6);
  const int cl   = __builtin_amdgcn_readfirstlane(wv * 4);  // local co base
  const int co0  = z * 32 + cl;

  const float* xb = x + (size_t)b * T * 64;
  for (int e = tid; e < 16 * XT; e += 512) { // transpose to [ci][t], swizzled
    int tl = e >> 4, cq = (e & 15) * 4;
    int cs = tl ^ (((cq >> 2) & 7) << 1);    // rows cq..cq+3 share cq>>2
    int gt = t0 - DIL + tl;
    float4 v = make_float4(0.f, 0.f, 0.f, 0.f);
    if ((unsigned)gt < (unsigned)T) v = *(const float4*)&xb[(size_t)gt * 64 + cq];
    xs[(cq + 0) * XS + cs] = v.x;
    xs[(cq + 1) * XS + cs] = v.y;
    xs[(cq + 2) * XS + cs] = v.z;
    xs[(cq + 3) * XS + cs] = v.w;
  }
  for (int e = tid; e < 1536; e += 512) {    // stage w[k][ci][z*32..+31]
    int c = (e & 7) * 4, rr = e >> 3;        // rr = k*64+ci
    *(float4*)&ws[rr * 32 + c] = *(const float4*)&w[rr * 64 + z * 32 + c];
  }
  __syncthreads();

  float acc[2][4] = {};
  const int tb = 2 * lane;
  for (int ci = 0; ci < 64; ++ci) {
    const int swz = ((ci >> 2) & 7) << 1;
    const float* xr = xs + ci * XS;
    float xv[NV];
    #pragma unroll
    for (int q = 0; q < NV / 2; ++q) {       // 8B-aligned -> ds_read_b64
      float2 v = *(const float2*)&xr[(tb + 2 * q) ^ swz];
      xv[2*q] = v.x; xv[2*q+1] = v.y;
    }
    float4 W0 = *(const float4*)&ws[(0 * 64 + ci) * 32 + cl];  // broadcast
    float4 W1 = *(const float4*)&ws[(1 * 64 + ci) * 32 + cl];
    float4 W2 = *(const float4*)&ws[(2 * 64 + ci) * 32 + cl];
    float c0[4] = {W0.x, W0.y, W0.z, W0.w};
    float c1[4] = {W1.x, W1.y, W1.z, W1.w};
    float c2[4] = {W2.x, W2.y, W2.z, W2.w};
    #pragma unroll
    for (int j = 0; j < 4; ++j) {
      #pragma unroll
      for (int i = 0; i < 2; ++i)
        acc[i][j] = fmaf(xv[i], c0[j], fmaf(xv[i + DIL], c1[j], fmaf(xv[i + 2 * DIL], c2[j], acc[i][j])));
    }
  }

  float bs[4];
  #pragma unroll
  for (int j = 0; j < 4; ++j) bs[j] = bias[co0 + j];
  #pragma unroll
  for (int i = 0; i < 2; ++i) {
    size_t o = ((size_t)b * T + t0 + tb + i) * 64 + co0;
    float r[4];
    #pragma unroll
    for (int j = 0; j < 4; ++j) r[j] = fmaxf(acc[i][j] + bs[j], 0.f);
    if (HAS_RES) {
      float4 v0 = *(const float4*)&res[o];
      r[0] += v0.x; r[1] += v0.y; r[2] += v0.z; r[3] += v0.w;
    }
    *(float4*)&y[o] = make_float4(r[0], r[1], r[2], r[3]);
  }
}

// ---------------- down2: K=4 stride2, 64->64, relu (unchanged) ------------
__global__ __launch_bounds__(512, 8) void down2_kernel(
    const float* __restrict__ x, const float* __restrict__ w,
    const float* __restrict__ bias, float* __restrict__ y, int Tin)
{
  constexpr int XT = 130, XS = 144;          // swizzle-safe stride
  __shared__ float xs[64 * XS];
  const int tid  = threadIdx.x;
  const int lane = tid & 63;
  const int b    = blockIdx.y;
  const int t0   = blockIdx.x * 64;
  const int Tout = Tin >> 1;
  const int wv   = __builtin_amdgcn_readfirstlane(tid >> 6);
  const int co0  = __builtin_amdgcn_readfirstlane(wv * 8);

  const float* xb = x + (size_t)b * Tin * 64;
  for (int e = tid; e < 16 * XT; e += 512) {
    int tl = e >> 4, cq = (e & 15) * 4;
    int cs = tl ^ (((cq >> 2) & 7) << 1);
    int gt = 2 * t0 - 1 + tl;
    float4 v = make_float4(0.f, 0.f, 0.f, 0.f);
    if ((unsigned)gt < (unsigned)Tin) v = *(const float4*)&xb[(size_t)gt * 64 + cq];
    xs[(cq + 0) * XS + cs] = v.x;
    xs[(cq + 1) * XS + cs] = v.y;
    xs[(cq + 2) * XS + cs] = v.z;
    xs[(cq + 3) * XS + cs] = v.w;
  }
  __syncthreads();

  float acc[8] = {};
  const float* wb = w + co0;
  for (int ci = 0; ci < 64; ++ci) {
    const int swz = ((ci >> 2) & 7) << 1;
    const float* xr = xs + ci * XS;
    float2 v0 = *(const float2*)&xr[(2 * lane) ^ swz];
    float2 v1 = *(const float2*)&xr[(2 * lane + 2) ^ swz];
    float a0 = v0.x, a1 = v0.y, a2 = v1.x, a3 = v1.y;
    const float* w0 = wb + (0 * 64 + ci) * 64;
    const float* w1 = wb + (1 * 64 + ci) * 64;
    const float* w2 = wb + (2 * 64 + ci) * 64;
    const float* w3 = wb + (3 * 64 + ci) * 64;
    #pragma unroll
    for (int j = 0; j < 8; ++j)
      acc[j] = fmaf(a0, w0[j], fmaf(a1, w1[j], fmaf(a2, w2[j], fmaf(a3, w3[j], acc[j]))));
  }

  size_t o = ((size_t)b * Tout + t0 + lane) * 64 + co0;
  #pragma unroll
  for (int q = 0; q < 2; ++q) {
    float4 rr;
    rr.x = fmaxf(acc[4*q+0] + bias[co0 + 4*q+0], 0.f);
    rr.y = fmaxf(acc[4*q+1] + bias[co0 + 4*q+1], 0.f);
    rr.z = fmaxf(acc[4*q+2] + bias[co0 + 4*q+2], 0.f);
    rr.w = fmaxf(acc[4*q+3] + bias[co0 + 4*q+3], 0.f);
    *(float4*)&y[o + 4 * q] = rr;
  }
}

// ---------------- up: conv_transpose K=4 stride2, 64->64, relu (r10) ------
__global__ __launch_bounds__(512, 8) void up_kernel(
    const float* __restrict__ x, const float* __restrict__ w,
    const float* __restrict__ bias, float* __restrict__ y, int Tin)
{
  constexpr int XT = 66, XS = 80;            // swizzle-safe stride
  __shared__ float xs[64 * XS];
  const int tid  = threadIdx.x;
  const int lane = tid & 63;
  const int b    = blockIdx.y;
  const int u0   = blockIdx.x * 64;
  const int Tout = Tin << 1;
  const int wv   = __builtin_amdgcn_readfirstlane(tid >> 6);
  const int co0  = __builtin_amdgcn_readfirstlane(wv * 8);

  const float* xb = x + (size_t)b * Tin * 64;
  for (int e = tid; e < 16 * XT; e += 512) {
    int ul = e >> 4, cq = (e & 15) * 4;
    int cs = ul ^ (((cq >> 2) & 7) << 1);
    int gu = u0 - 1 + ul;
    float4 v = make_float4(0.f, 0.f, 0.f, 0.f);
    if ((unsigned)gu < (unsigned)Tin) v = *(const float4*)&xb[(size_t)gu * 64 + cq];
    xs[(cq + 0) * XS + cs] = v.x;
    xs[(cq + 1) * XS + cs] = v.y;
    xs[(cq + 2) * XS + cs] = v.z;
    xs[(cq + 3) * XS + cs] = v.w;
  }
  __syncthreads();

  float acce[8] = {}, acco[8] = {};
  const float* wb = w + co0;
  for (int ci = 0; ci < 64; ++ci) {
    const int swz = ((ci >> 2) & 7) << 1;
    const float* xr = xs + ci * XS;
    float a0 = xr[(lane) ^ swz];             // x[u-1]
    float a1 = xr[(lane + 1) ^ swz];         // x[u]
    float a2 = xr[(lane + 2) ^ swz];         // x[u+1]
    const float* w0 = wb + (0 * 64 + ci) * 64;
    const float* w1 = wb + (1 * 64 + ci) * 64;
    const float* w2 = wb + (2 * 64 + ci) * 64;
    const float* w3 = wb + (3 * 64 + ci) * 64;
    #pragma unroll
    for (int j = 0; j < 8; ++j) {
      acce[j] = fmaf(a0, w0[j], fmaf(a1, w2[j], acce[j]));
      acco[j] = fmaf(a1, w1[j], fmaf(a2, w3[j], acco[j]));
    }
  }

  size_t oe = ((size_t)b * Tout + 2 * (u0 + lane)) * 64 + co0;
  size_t oo = oe + 64;
  #pragma unroll
  for (int q = 0; q < 2; ++q) {
    float4 re, ro;
    re.x = fmaxf(acce[4*q+0] + bias[co0 + 4*q+0], 0.f);
    re.y = fmaxf(acce[4*q+1] + bias[co0 + 4*q+1], 0.f);
    re.z = fmaxf(acce[4*q+2] + bias[co0 + 4*q+2], 0.f);
    re.w = fmaxf(acce[4*q+3] + bias[co0 + 4*q+3], 0.f);
    ro.x = fmaxf(acco[4*q+0] + bias[co0 + 4*q+0], 0.f);
    ro.y = fmaxf(acco[4*q+1] + bias[co0 + 4*q+1], 0.f);
    ro.z = fmaxf(acco[4*q+2] + bias[co0 + 4*q+2], 0.f);
    ro.w = fmaxf(acco[4*q+3] + bias[co0 + 4*q+3], 0.f);
    *(float4*)&y[oe + 4 * q] = re;
    *(float4*)&y[oo + 4 * q] = ro;
  }
}

// ---------------- proj: K=3 dil1, 64->1, linear ---------------------------
__global__ __launch_bounds__(256) void proj_kernel(
    const float* __restrict__ x, const float* __restrict__ w,
    const float* __restrict__ bias, float* __restrict__ out)
{
  const int lane = threadIdx.x & 63;
  const int wid  = (blockIdx.x * 256 + threadIdx.x) >> 6;  // 4096 waves
  const float w0 = w[lane], w1 = w[64 + lane], w2 = w[128 + lane];
  const float bb = bias[0];
  size_t base = (size_t)wid * 64;
  for (int i = 0; i < 64; ++i) {
    size_t tau = base + i;
    int b = (int)(tau >> 16);
    int t = (int)(tau & 65535);
    const float* xb = x + ((size_t)b * 65536) * 64;
    float pm = (t > 0)     ? xb[(size_t)(t - 1) * 64 + lane] : 0.f;
    float pc =               xb[(size_t)t * 64 + lane];
    float pp = (t < 65535) ? xb[(size_t)(t + 1) * 64 + lane] : 0.f;
    float s = pm * w0 + pc * w1 + pp * w2;
    #pragma unroll
    for (int off = 32; off; off >>= 1) s += __shfl_down(s, off);
    if (lane == 0) out[tau] = s + bb;
  }
}

// ---------------- nz: per-token sum of squares ----------------------------
__global__ __launch_bounds__(256) void nz_kernel(
    const float* __restrict__ ze, float* __restrict__ nz)
{
  int lane = threadIdx.x & 63;
  int tok  = (blockIdx.x * 256 + threadIdx.x) >> 6;
  float v = ze[(size_t)tok * 64 + lane];
  float s = v * v;
  #pragma unroll
  for (int off = 32; off; off >>= 1) s += __shfl_down(s, off);
  if (lane == 0) nz[tok] = s;
}

// ---------------- ne: per-entry codebook norm (512 entries, once) ---------
__global__ __launch_bounds__(256) void ne_kernel(
    const float* __restrict__ cb, float* __restrict__ ne)
{
  int c = blockIdx.x * 256 + threadIdx.x;   // grid 2 -> 512 entries
  const float4* p = (const float4*)(cb + (size_t)c * 64);
  float s = 0.f;
  #pragma unroll
  for (int q = 0; q < 16; ++q) {
    float4 v = p[q];
    s += v.x * v.x + v.y * v.y + v.z * v.z + v.w * v.w;
  }
  ne[c] = s;
}

// ---------------- vq_dots: register-blocked GEMM --------------------------
__global__ __launch_bounds__(256) void vq_dots_kernel(
    const float* __restrict__ ze, const float* __restrict__ cb,
    const float* __restrict__ nzbuf, const float* __restrict__ nebuf,
    float* __restrict__ sim_out, float2* __restrict__ pmin)
{
  constexpr int ZS = 68, CS = 132;
  __shared__ float zt[64 * ZS];              // [d][tok]   17.4 KB
  __shared__ float ct[64 * CS];              // [d][ent]   33.8 KB
  const int tid = threadIdx.x;
  const int tx  = tid & 15;                  // entry group (8 entries)
  const int ty  = tid >> 4;                  // token group (4 tokens)
  const int bx  = blockIdx.x, by = blockIdx.y;

  {                                          // stage z tile (transpose, swz)
    const float* zb = ze + (size_t)bx * 64 * 64;
    #pragma unroll
    for (int it = 0; it < 4; ++it) {
      int e = tid + it * 256;
      int tl = e >> 4, cq = (e & 15) * 4;
      int cs = tl ^ (((cq >> 2) & 7) << 2);
      float4 v = *(const float4*)&zb[tl * 64 + cq];
      zt[(cq + 0) * ZS + cs] = v.x;
      zt[(cq + 1) * ZS + cs] = v.y;
      zt[(cq + 2) * ZS + cs] = v.z;
      zt[(cq + 3) * ZS + cs] = v.w;
    }
    const float* cbb = cb + (size_t)by * 128 * 64;
    #pragma unroll
    for (int it = 0; it < 8; ++it) {
      int e = tid + it * 256;
      int el = e >> 4, cq = (e & 15) * 4;
      int cs = el ^ (((cq >> 2) & 7) << 2);
      float4 v = *(const float4*)&cbb[el * 64 + cq];
      ct[(cq + 0) * CS + cs] = v.x;
      ct[(cq + 1) * CS + cs] = v.y;
      ct[(cq + 2) * CS + cs] = v.z;
      ct[(cq + 3) * CS + cs] = v.w;
    }
  }
  __syncthreads();

  float acc[4][8] = {};
  #pragma unroll 4
  for (int k = 0; k < 64; ++k) {
    const int swz = ((k >> 2) & 7) << 2;
    float4 zv = *(const float4*)&zt[k * ZS + ((ty * 4) ^ swz)];
    float4 c0 = *(const float4*)&ct[k * CS + ((tx * 8) ^ swz)];
    float4 c1 = *(const float4*)&ct[k * CS + ((tx * 8 + 4) ^ swz)];
    float zr[4] = {zv.x, zv.y, zv.z, zv.w};
    float cr[8] = {c0.x, c0.y, c0.z, c0.w, c1.x, c1.y, c1.z, c1.w};
    #pragma unroll
    for (int i = 0; i < 4; ++i)
      #pragma unroll
      for (int j = 0; j < 8; ++j)
        acc[i][j] = fmaf(zr[i], cr[j], acc[i][j]);
  }

  // epilogue: dist, sim, argmin partials
  float4 nzq = *(const float4*)&nzbuf[bx * 64 + ty * 4];
  float nzv[4] = {nzq.x, nzq.y, nzq.z, nzq.w};
  float4 ne0  = *(const float4*)&nebuf[by * 128 + tx * 8];
  float4 ne1  = *(const float4*)&nebuf[by * 128 + tx * 8 + 4];
  float nev[8]  = {ne0.x, ne0.y, ne0.z, ne0.w, ne1.x, ne1.y, ne1.z, ne1.w};
  float rsne[8];
  #pragma unroll
  for (int j = 0; j < 8; ++j) rsne[j] = 1.f / sqrtf(nev[j]);
  const int ent0 = by * 128 + tx * 8;

  #pragma unroll
  for (int i = 0; i < 4; ++i) {
    const int tok = bx * 64 + ty * 4 + i;
    const float rsnz = 1.f / sqrtf(nzv[i]);
    float dist[8], simv[8];
    #pragma unroll
    for (int j = 0; j < 8; ++j) {
      dist[j] = (-2.f * acc[i][j] + nzv[i]) + nev[j];
      simv[j] = acc[i][j] * rsnz * rsne[j];
    }
    float* so = sim_out + (size_t)tok * 512 + ent0;
    *(float4*)&so[0] = make_float4(simv[0], simv[1], simv[2], simv[3]);
    *(float4*)&so[4] = make_float4(simv[4], simv[5], simv[6], simv[7]);

    float md = dist[0]; int mi = ent0;       // ascending strict < -> lowest j
    #pragma unroll
    for (int j = 1; j < 8; ++j)
      if (dist[j] < md) { md = dist[j]; mi = ent0 + j; }
    #pragma unroll
    for (int off = 1; off < 16; off <<= 1) { // reduce across 16-lane tx group
      float od = __shfl_xor(md, off);
      int   oi = __shfl_xor(mi, off);
      if (od < md || (od == md && oi < mi)) { md = od; mi = oi; }
    }
    if (tx == 0) pmin[tok * 4 + by] = make_float2(md, (float)mi);
  }
}

// ---------------- vq_finish: cross-partial argmin, z_q, ids, loss ---------
__global__ __launch_bounds__(256) void vq_finish_kernel(
    const float* __restrict__ ze, const float* __restrict__ cb,
    const float2* __restrict__ pmin, float* __restrict__ zq,
    float* __restrict__ ids_out, float* __restrict__ blocksum)
{
  const int tid = threadIdx.x;
  const int lane = tid & 63, wvid = tid >> 6;
  float lloss = 0.f;
  for (int it = 0; it < 16; ++it) {
    const int tok = blockIdx.x * 64 + wvid * 16 + it;
    float bd = 1e30f; int bi = 0;
    #pragma unroll
    for (int p = 0; p < 4; ++p) {            // 4 entry-tile partials, ascending
      float2 pr = pmin[tok * 4 + p];
      float d = pr.x; int i = (int)pr.y;
      if (d < bd || (d == bd && i < bi)) { bd = d; bi = i; }
    }
    float zev = ze[(size_t)tok * 64 + lane];
    float cv  = cb[(size_t)bi * 64 + lane];
    float df = zev - cv;
    float s = df * df;
    #pragma unroll
    for (int off = 32; off; off >>= 1) s += __shfl_down(s, off);
    zq[(size_t)tok * 64 + lane] = cv;
    if (lane == 0) { ids_out[tok] = (float)bi; lloss += sqrtf(s); }
  }
  __shared__ float ls[4];
  if (lane == 0) ls[wvid] = lloss;
  __syncthreads();
  if (tid == 0) blocksum[blockIdx.x] = ls[0] + ls[1] + ls[2] + ls[3];
}

__global__ void loss_fin_kernel(const float* __restrict__ blocksum,
                                float* __restrict__ out)
{
  const int lane = threadIdx.x;  // 64 threads
  float s = 0.f;
  for (int i = lane; i < 512; i += 64) s += blocksum[i];
  #pragma unroll
  for (int off = 32; off; off >>= 1) s += __shfl_down(s, off);
  if (lane == 0) out[0] = 1.25f * s / 32768.f;
}

// ---------------------------------------------------------------------------
#define LAUNCH_CONV3(DILV, RESV, XP, WP, BP, RP, YP)                           \
  conv3_kernel<DILV, RESV><<<dim3(T / 128, 4, 2), 512, 0, stream>>>(           \
      XP, WP, BP, RP, YP, T)

extern "C" void kernel_launch(void* const* d_in, const int* in_sizes, int n_in,
                              void* d_out, int out_size, void* d_ws, size_t ws_size,
                              hipStream_t stream)
{
  const float* x       = (const float*)d_in[0];
  const float* w_down0 = (const float*)d_in[1];
  const float* b_down0 = (const float*)d_in[2];
  const float* w_down  = (const float*)d_in[3];
  const float* b_down  = (const float*)d_in[4];
  const float* w_res_e = (const float*)d_in[5];
  const float* b_res_e = (const float*)d_in[6];
  const float* cb      = (const float*)d_in[7];
  const float* w_res_d = (const float*)d_in[8];
  const float* b_res_d = (const float*)d_in[9];
  const float* w_up    = (const float*)d_in[10];
  const float* b_up    = (const float*)d_in[11];
  const float* w_proj  = (const float*)d_in[12];
  const float* b_proj  = (const float*)d_in[13];

  float* out = (float*)d_out;
  const size_t BUF = (size_t)4 * 65536 * 64;
  float*  bufA     = (float*)d_ws;
  float*  bufB     = bufA + BUF;
  float*  nzbuf    = bufB + BUF;
  float*  nebuf    = nzbuf + 32768;
  float2* pmin     = (float2*)(nebuf + 512);
  float*  blocksum = (float*)(pmin + 32768 * 4);

  float* h = bufA;
  float* tmp = bufB;

  // ---- encoder ----
  down0_kernel<<<32768, 256, 0, stream>>>(x, w_down0, b_down0, h);
  int T = 32768;
  for (int blk = 0; blk < 3; ++blk) {
    if (blk > 0) {
      down2_kernel<<<dim3(T / 2 / 64, 4), 512, 0, stream>>>(
          h, w_down + (size_t)(blk - 1) * 4 * 64 * 64, b_down + (blk - 1) * 64, tmp, T);
      T >>= 1;
      float* s = h; h = tmp; tmp = s;
    }
    for (int r = 0; r < 4; ++r) {
      const float* w0p = w_res_e + (((size_t)blk * 4 + r) * 2 + 0) * 3 * 64 * 64;
      const float* w1p = w_res_e + (((size_t)blk * 4 + r) * 2 + 1) * 3 * 64 * 64;
      const float* b0p = b_res_e + (((size_t)blk * 4 + r) * 2 + 0) * 64;
      const float* b1p = b_res_e + (((size_t)blk * 4 + r) * 2 + 1) * 64;
      LAUNCH_CONV3(3, false, h, w0p, b0p, nullptr, tmp);
      LAUNCH_CONV3(1, true,  tmp, w1p, b1p, h, h);
    }
  }

  // ---- VQ (T == 8192, z_e in h; 32768 tokens) ----
  nz_kernel<<<8192, 256, 0, stream>>>(h, nzbuf);
  ne_kernel<<<2, 256, 0, stream>>>(cb, nebuf);
  vq_dots_kernel<<<dim3(512, 4), 256, 0, stream>>>(h, cb, nzbuf, nebuf, out + OFF_SIM, pmin);
  vq_finish_kernel<<<512, 256, 0, stream>>>(h, cb, pmin, tmp, out + OFF_IDS, blocksum);
  loss_fin_kernel<<<1, 64, 0, stream>>>(blocksum, out + OFF_LOSS);
  { float* s = h; h = tmp; tmp = s; }  // h = z_q

  // ---- decoder ----
  for (int blk = 0; blk < 3; ++blk) {
    for (int r = 0; r < 4; ++r) {
      const float* w0p = w_res_d + (((size_t)blk * 4 + r) * 2 + 0) * 3 * 64 * 64;
      const float* w1p = w_res_d + (((size_t)blk * 4 + r) * 2 + 1) * 3 * 64 * 64;
      const float* b0p = b_res_d + (((size_t)blk * 4 + r) * 2 + 0) * 64;
      const float* b1p = b_res_d + (((size_t)blk * 4 + r) * 2 + 1) * 64;
      LAUNCH_CONV3(1, false, h, w0p, b0p, nullptr, tmp);
      LAUNCH_CONV3(3, true,  tmp, w1p, b1p, h, h);
    }
    up_kernel<<<dim3(2 * T / 128, 4), 512, 0, stream>>>(
        h, w_up + (size_t)blk * 4 * 64 * 64, b_up + blk * 64, tmp, T);
    T <<= 1;
    float* s = h; h = tmp; tmp = s;
  }

  // ---- final projection (T == 65536) ----
  proj_kernel<<<1024, 256, 0, stream>>>(h, w_proj, b_proj, out);
}

// Round 7
// 1777.185 us; speedup vs baseline: 1.1474x; 1.1474x over previous
//
#include <hip/hip_runtime.h>
#include <cstdint>

// ---------------------------------------------------------------------------
// JukeboxAutoEncoder fp32, round 14.
// r13 post-mortem: weights->LDS put 3 ds_read_b128/ci on the same DS pipe as
//   x reads (60cy DS vs 48cy FMA) + double x staging -> DS-bound, 2039us.
//   Scalar s_load weights + ds_read x (r10) is the right pipe split.
// This round: conv3 restored to r10 for T<=16384; NEW TPL=4 (TT=256) variant
//   for T=32768 (16 dispatches, biggest term): 96 FMA per ci against the same
//   24 scalar loads + 3 DS reads -> 2x FMA per lgkmcnt drain. x reads are
//   16B ds_read_b128 (4*lane covers 32 banks; b64@stride4 would be 4-way),
//   swizzle <<2, XS=288 (in-row), 73.7KB LDS -> 2 blk/CU, bounds (512,4).
// Output layout (flat f32): x_hat[262144] | loss_vq[1] | ids[32768] | sim[16777216]
// ---------------------------------------------------------------------------

#define OFF_LOSS 262144
#define OFF_IDS  262145
#define OFF_SIM  294913

// ---------------- down0: (B,65536,1) -> (B,32768,64), K=4 stride2, relu ----
__global__ __launch_bounds__(256) void down0_kernel(
    const float* __restrict__ x, const float* __restrict__ w,
    const float* __restrict__ bias, float* __restrict__ y)
{
  int idx = blockIdx.x * 256 + threadIdx.x;   // enumerates (b, t, co)
  int co = idx & 63;
  int r  = idx >> 6;
  int t  = r & 32767;
  int b  = r >> 15;
  const float* xb = x + (size_t)b * 65536;
  float acc = bias[co];
  #pragma unroll
  for (int k = 0; k < 4; ++k) {
    int gt = 2 * t - 1 + k;
    float xv = ((unsigned)gt < 65536u) ? xb[gt] : 0.f;
    acc += xv * w[k * 64 + co];
  }
  y[(size_t)idx] = fmaxf(acc, 0.f);
}

// ---------------- conv3: K=3, dil DIL, 64->64, relu, optional +res --------
// 512 thr = 8 waves; wave wv owns co0 = wv*8 (wave-uniform -> s_load weights);
// lane covers t = t0 + TPL*lane + i, i<TPL. grid (T/TT, 4).
// TPL=4 (TT=256): b128 x reads, swizzle <<2, XS mult of 32.
template <int DIL, bool HAS_RES, int TT>
__global__ __launch_bounds__(512, (TT == 256 ? 4 : 8)) void conv3_kernel(
    const float* __restrict__ x, const float* __restrict__ w,
    const float* __restrict__ bias, const float* res,
    float* y, int T)
{
  constexpr int TPL = TT / 64;               // 1, 2 or 4 t per lane
  constexpr int XT  = TT + 2 * DIL;
  constexpr int SW  = (TPL == 4) ? 2 : 1;    // swizzle shift (b128 vs b64 safe)
  constexpr int XS  = (TPL == 4) ? (((XT - 1) | 31) + 1)
                                 : (((XT - 1) | 15) + 1);
  constexpr int NV  = TPL + 2 * DIL;
  __shared__ float xs[64 * XS];
  const int tid  = threadIdx.x;
  const int lane = tid & 63;
  const int b    = blockIdx.y;
  const int t0   = blockIdx.x * TT;
  const int wv   = __builtin_amdgcn_readfirstlane(tid >> 6);
  const int co0  = __builtin_amdgcn_readfirstlane(wv * 8);

  const float* xb = x + (size_t)b * T * 64;
  for (int e = tid; e < 16 * XT; e += 512) { // transpose to [ci][t], swizzled
    int tl = e >> 4, cq = (e & 15) * 4;
    int cs = tl ^ (((cq >> 2) & 7) << SW);   // rows cq..cq+3 share cq>>2
    int gt = t0 - DIL + tl;
    float4 v = make_float4(0.f, 0.f, 0.f, 0.f);
    if ((unsigned)gt < (unsigned)T) v = *(const float4*)&xb[(size_t)gt * 64 + cq];
    xs[(cq + 0) * XS + cs] = v.x;
    xs[(cq + 1) * XS + cs] = v.y;
    xs[(cq + 2) * XS + cs] = v.z;
    xs[(cq + 3) * XS + cs] = v.w;
  }
  __syncthreads();

  float acc[TPL][8] = {};
  const float* wb = w + co0;                 // w[k][ci][co0..co0+7]
  const int tb = TPL * lane;
  for (int ci = 0; ci < 64; ++ci) {
    const int swz = ((ci >> 2) & 7) << SW;
    const float* xr = xs + ci * XS;
    float xv[NV];
    if constexpr (TPL == 4) {                // 16B-aligned -> ds_read_b128
      float4 v0 = *(const float4*)&xr[tb ^ swz];
      xv[0] = v0.x; xv[1] = v0.y; xv[2] = v0.z; xv[3] = v0.w;
      if constexpr (DIL == 3) {              // NV = 10
        float4 v1 = *(const float4*)&xr[(tb + 4) ^ swz];
        float2 v2 = *(const float2*)&xr[(tb + 8) ^ swz];
        xv[4] = v1.x; xv[5] = v1.y; xv[6] = v1.z; xv[7] = v1.w;
        xv[8] = v2.x; xv[9] = v2.y;
      } else {                               // NV = 6
        float2 v1 = *(const float2*)&xr[(tb + 4) ^ swz];
        xv[4] = v1.x; xv[5] = v1.y;
      }
    } else if constexpr (TPL == 2) {         // 8B-aligned -> ds_read_b64
      #pragma unroll
      for (int q = 0; q < NV / 2; ++q) {
        float2 v = *(const float2*)&xr[(tb + 2 * q) ^ swz];
        xv[2*q] = v.x; xv[2*q+1] = v.y;
      }
    } else {
      #pragma unroll
      for (int j = 0; j < NV; ++j) xv[j] = xr[(tb + j) ^ swz];
    }
    const float* w0 = wb + (0 * 64 + ci) * 64;
    const float* w1 = wb + (1 * 64 + ci) * 64;
    const float* w2 = wb + (2 * 64 + ci) * 64;
    #pragma unroll
    for (int j = 0; j < 8; ++j) {
      float c0 = w0[j], c1 = w1[j], c2 = w2[j];
      #pragma unroll
      for (int i = 0; i < TPL; ++i)
        acc[i][j] = fmaf(xv[i], c0, fmaf(xv[i + DIL], c1, fmaf(xv[i + 2 * DIL], c2, acc[i][j])));
    }
  }

  float bs[8];
  #pragma unroll
  for (int j = 0; j < 8; ++j) bs[j] = bias[co0 + j];
  #pragma unroll
  for (int i = 0; i < TPL; ++i) {
    size_t o = ((size_t)b * T + t0 + tb + i) * 64 + co0;
    float r[8];
    #pragma unroll
    for (int j = 0; j < 8; ++j) r[j] = fmaxf(acc[i][j] + bs[j], 0.f);
    if (HAS_RES) {
      float4 v0 = *(const float4*)&res[o];
      float4 v1 = *(const float4*)&res[o + 4];
      r[0] += v0.x; r[1] += v0.y; r[2] += v0.z; r[3] += v0.w;
      r[4] += v1.x; r[5] += v1.y; r[6] += v1.z; r[7] += v1.w;
    }
    *(float4*)&y[o]     = make_float4(r[0], r[1], r[2], r[3]);
    *(float4*)&y[o + 4] = make_float4(r[4], r[5], r[6], r[7]);
  }
}

// ---------------- down2: K=4 stride2, 64->64, relu ------------------------
__global__ __launch_bounds__(512, 8) void down2_kernel(
    const float* __restrict__ x, const float* __restrict__ w,
    const float* __restrict__ bias, float* __restrict__ y, int Tin)
{
  constexpr int XT = 130, XS = 144;          // swizzle-safe stride
  __shared__ float xs[64 * XS];
  const int tid  = threadIdx.x;
  const int lane = tid & 63;
  const int b    = blockIdx.y;
  const int t0   = blockIdx.x * 64;
  const int Tout = Tin >> 1;
  const int wv   = __builtin_amdgcn_readfirstlane(tid >> 6);
  const int co0  = __builtin_amdgcn_readfirstlane(wv * 8);

  const float* xb = x + (size_t)b * Tin * 64;
  for (int e = tid; e < 16 * XT; e += 512) {
    int tl = e >> 4, cq = (e & 15) * 4;
    int cs = tl ^ (((cq >> 2) & 7) << 1);
    int gt = 2 * t0 - 1 + tl;
    float4 v = make_float4(0.f, 0.f, 0.f, 0.f);
    if ((unsigned)gt < (unsigned)Tin) v = *(const float4*)&xb[(size_t)gt * 64 + cq];
    xs[(cq + 0) * XS + cs] = v.x;
    xs[(cq + 1) * XS + cs] = v.y;
    xs[(cq + 2) * XS + cs] = v.z;
    xs[(cq + 3) * XS + cs] = v.w;
  }
  __syncthreads();

  float acc[8] = {};
  const float* wb = w + co0;
  for (int ci = 0; ci < 64; ++ci) {
    const int swz = ((ci >> 2) & 7) << 1;
    const float* xr = xs + ci * XS;
    float2 v0 = *(const float2*)&xr[(2 * lane) ^ swz];
    float2 v1 = *(const float2*)&xr[(2 * lane + 2) ^ swz];
    float a0 = v0.x, a1 = v0.y, a2 = v1.x, a3 = v1.y;
    const float* w0 = wb + (0 * 64 + ci) * 64;
    const float* w1 = wb + (1 * 64 + ci) * 64;
    const float* w2 = wb + (2 * 64 + ci) * 64;
    const float* w3 = wb + (3 * 64 + ci) * 64;
    #pragma unroll
    for (int j = 0; j < 8; ++j)
      acc[j] = fmaf(a0, w0[j], fmaf(a1, w1[j], fmaf(a2, w2[j], fmaf(a3, w3[j], acc[j]))));
  }

  size_t o = ((size_t)b * Tout + t0 + lane) * 64 + co0;
  #pragma unroll
  for (int q = 0; q < 2; ++q) {
    float4 rr;
    rr.x = fmaxf(acc[4*q+0] + bias[co0 + 4*q+0], 0.f);
    rr.y = fmaxf(acc[4*q+1] + bias[co0 + 4*q+1], 0.f);
    rr.z = fmaxf(acc[4*q+2] + bias[co0 + 4*q+2], 0.f);
    rr.w = fmaxf(acc[4*q+3] + bias[co0 + 4*q+3], 0.f);
    *(float4*)&y[o + 4 * q] = rr;
  }
}

// ---------------- up: conv_transpose K=4 stride2, 64->64, relu ------------
__global__ __launch_bounds__(512, 8) void up_kernel(
    const float* __restrict__ x, const float* __restrict__ w,
    const float* __restrict__ bias, float* __restrict__ y, int Tin)
{
  constexpr int XT = 66, XS = 80;            // swizzle-safe stride
  __shared__ float xs[64 * XS];
  const int tid  = threadIdx.x;
  const int lane = tid & 63;
  const int b    = blockIdx.y;
  const int u0   = blockIdx.x * 64;
  const int Tout = Tin << 1;
  const int wv   = __builtin_amdgcn_readfirstlane(tid >> 6);
  const int co0  = __builtin_amdgcn_readfirstlane(wv * 8);

  const float* xb = x + (size_t)b * Tin * 64;
  for (int e = tid; e < 16 * XT; e += 512) {
    int ul = e >> 4, cq = (e & 15) * 4;
    int cs = ul ^ (((cq >> 2) & 7) << 1);
    int gu = u0 - 1 + ul;
    float4 v = make_float4(0.f, 0.f, 0.f, 0.f);
    if ((unsigned)gu < (unsigned)Tin) v = *(const float4*)&xb[(size_t)gu * 64 + cq];
    xs[(cq + 0) * XS + cs] = v.x;
    xs[(cq + 1) * XS + cs] = v.y;
    xs[(cq + 2) * XS + cs] = v.z;
    xs[(cq + 3) * XS + cs] = v.w;
  }
  __syncthreads();

  float acce[8] = {}, acco[8] = {};
  const float* wb = w + co0;
  for (int ci = 0; ci < 64; ++ci) {
    const int swz = ((ci >> 2) & 7) << 1;
    const float* xr = xs + ci * XS;
    float a0 = xr[(lane) ^ swz];             // x[u-1]
    float a1 = xr[(lane + 1) ^ swz];         // x[u]
    float a2 = xr[(lane + 2) ^ swz];         // x[u+1]
    const float* w0 = wb + (0 * 64 + ci) * 64;
    const float* w1 = wb + (1 * 64 + ci) * 64;
    const float* w2 = wb + (2 * 64 + ci) * 64;
    const float* w3 = wb + (3 * 64 + ci) * 64;
    #pragma unroll
    for (int j = 0; j < 8; ++j) {
      acce[j] = fmaf(a0, w0[j], fmaf(a1, w2[j], acce[j]));
      acco[j] = fmaf(a1, w1[j], fmaf(a2, w3[j], acco[j]));
    }
  }

  size_t oe = ((size_t)b * Tout + 2 * (u0 + lane)) * 64 + co0;
  size_t oo = oe + 64;
  #pragma unroll
  for (int q = 0; q < 2; ++q) {
    float4 re, ro;
    re.x = fmaxf(acce[4*q+0] + bias[co0 + 4*q+0], 0.f);
    re.y = fmaxf(acce[4*q+1] + bias[co0 + 4*q+1], 0.f);
    re.z = fmaxf(acce[4*q+2] + bias[co0 + 4*q+2], 0.f);
    re.w = fmaxf(acce[4*q+3] + bias[co0 + 4*q+3], 0.f);
    ro.x = fmaxf(acco[4*q+0] + bias[co0 + 4*q+0], 0.f);
    ro.y = fmaxf(acco[4*q+1] + bias[co0 + 4*q+1], 0.f);
    ro.z = fmaxf(acco[4*q+2] + bias[co0 + 4*q+2], 0.f);
    ro.w = fmaxf(acco[4*q+3] + bias[co0 + 4*q+3], 0.f);
    *(float4*)&y[oe + 4 * q] = re;
    *(float4*)&y[oo + 4 * q] = ro;
  }
}

// ---------------- proj: K=3 dil1, 64->1, linear ---------------------------
__global__ __launch_bounds__(256) void proj_kernel(
    const float* __restrict__ x, const float* __restrict__ w,
    const float* __restrict__ bias, float* __restrict__ out)
{
  const int lane = threadIdx.x & 63;
  const int wid  = (blockIdx.x * 256 + threadIdx.x) >> 6;  // 4096 waves
  const float w0 = w[lane], w1 = w[64 + lane], w2 = w[128 + lane];
  const float bb = bias[0];
  size_t base = (size_t)wid * 64;
  for (int i = 0; i < 64; ++i) {
    size_t tau = base + i;
    int b = (int)(tau >> 16);
    int t = (int)(tau & 65535);
    const float* xb = x + ((size_t)b * 65536) * 64;
    float pm = (t > 0)     ? xb[(size_t)(t - 1) * 64 + lane] : 0.f;
    float pc =               xb[(size_t)t * 64 + lane];
    float pp = (t < 65535) ? xb[(size_t)(t + 1) * 64 + lane] : 0.f;
    float s = pm * w0 + pc * w1 + pp * w2;
    #pragma unroll
    for (int off = 32; off; off >>= 1) s += __shfl_down(s, off);
    if (lane == 0) out[tau] = s + bb;
  }
}

// ---------------- nz: per-token sum of squares ----------------------------
__global__ __launch_bounds__(256) void nz_kernel(
    const float* __restrict__ ze, float* __restrict__ nz)
{
  int lane = threadIdx.x & 63;
  int tok  = (blockIdx.x * 256 + threadIdx.x) >> 6;
  float v = ze[(size_t)tok * 64 + lane];
  float s = v * v;
  #pragma unroll
  for (int off = 32; off; off >>= 1) s += __shfl_down(s, off);
  if (lane == 0) nz[tok] = s;
}

// ---------------- ne: per-entry codebook norm (512 entries, once) ---------
__global__ __launch_bounds__(256) void ne_kernel(
    const float* __restrict__ cb, float* __restrict__ ne)
{
  int c = blockIdx.x * 256 + threadIdx.x;   // grid 2 -> 512 entries
  const float4* p = (const float4*)(cb + (size_t)c * 64);
  float s = 0.f;
  #pragma unroll
  for (int q = 0; q < 16; ++q) {
    float4 v = p[q];
    s += v.x * v.x + v.y * v.y + v.z * v.z + v.w * v.w;
  }
  ne[c] = s;
}

// ---------------- vq_dots: register-blocked GEMM --------------------------
__global__ __launch_bounds__(256) void vq_dots_kernel(
    const float* __restrict__ ze, const float* __restrict__ cb,
    const float* __restrict__ nzbuf, const float* __restrict__ nebuf,
    float* __restrict__ sim_out, float2* __restrict__ pmin)
{
  constexpr int ZS = 68, CS = 132;
  __shared__ float zt[64 * ZS];              // [d][tok]   17.4 KB
  __shared__ float ct[64 * CS];              // [d][ent]   33.8 KB
  const int tid = threadIdx.x;
  const int tx  = tid & 15;                  // entry group (8 entries)
  const int ty  = tid >> 4;                  // token group (4 tokens)
  const int bx  = blockIdx.x, by = blockIdx.y;

  {                                          // stage z tile (transpose, swz)
    const float* zb = ze + (size_t)bx * 64 * 64;
    #pragma unroll
    for (int it = 0; it < 4; ++it) {
      int e = tid + it * 256;
      int tl = e >> 4, cq = (e & 15) * 4;
      int cs = tl ^ (((cq >> 2) & 7) << 2);
      float4 v = *(const float4*)&zb[tl * 64 + cq];
      zt[(cq + 0) * ZS + cs] = v.x;
      zt[(cq + 1) * ZS + cs] = v.y;
      zt[(cq + 2) * ZS + cs] = v.z;
      zt[(cq + 3) * ZS + cs] = v.w;
    }
    const float* cbb = cb + (size_t)by * 128 * 64;
    #pragma unroll
    for (int it = 0; it < 8; ++it) {
      int e = tid + it * 256;
      int el = e >> 4, cq = (e & 15) * 4;
      int cs = el ^ (((cq >> 2) & 7) << 2);
      float4 v = *(const float4*)&cbb[el * 64 + cq];
      ct[(cq + 0) * CS + cs] = v.x;
      ct[(cq + 1) * CS + cs] = v.y;
      ct[(cq + 2) * CS + cs] = v.z;
      ct[(cq + 3) * CS + cs] = v.w;
    }
  }
  __syncthreads();

  float acc[4][8] = {};
  #pragma unroll 4
  for (int k = 0; k < 64; ++k) {
    const int swz = ((k >> 2) & 7) << 2;
    float4 zv = *(const float4*)&zt[k * ZS + ((ty * 4) ^ swz)];
    float4 c0 = *(const float4*)&ct[k * CS + ((tx * 8) ^ swz)];
    float4 c1 = *(const float4*)&ct[k * CS + ((tx * 8 + 4) ^ swz)];
    float zr[4] = {zv.x, zv.y, zv.z, zv.w};
    float cr[8] = {c0.x, c0.y, c0.z, c0.w, c1.x, c1.y, c1.z, c1.w};
    #pragma unroll
    for (int i = 0; i < 4; ++i)
      #pragma unroll
      for (int j = 0; j < 8; ++j)
        acc[i][j] = fmaf(zr[i], cr[j], acc[i][j]);
  }

  // epilogue: dist, sim, argmin partials
  float4 nzq = *(const float4*)&nzbuf[bx * 64 + ty * 4];
  float nzv[4] = {nzq.x, nzq.y, nzq.z, nzq.w};
  float4 ne0  = *(const float4*)&nebuf[by * 128 + tx * 8];
  float4 ne1  = *(const float4*)&nebuf[by * 128 + tx * 8 + 4];
  float nev[8]  = {ne0.x, ne0.y, ne0.z, ne0.w, ne1.x, ne1.y, ne1.z, ne1.w};
  float rsne[8];
  #pragma unroll
  for (int j = 0; j < 8; ++j) rsne[j] = 1.f / sqrtf(nev[j]);
  const int ent0 = by * 128 + tx * 8;

  #pragma unroll
  for (int i = 0; i < 4; ++i) {
    const int tok = bx * 64 + ty * 4 + i;
    const float rsnz = 1.f / sqrtf(nzv[i]);
    float dist[8], simv[8];
    #pragma unroll
    for (int j = 0; j < 8; ++j) {
      dist[j] = (-2.f * acc[i][j] + nzv[i]) + nev[j];
      simv[j] = acc[i][j] * rsnz * rsne[j];
    }
    float* so = sim_out + (size_t)tok * 512 + ent0;
    *(float4*)&so[0] = make_float4(simv[0], simv[1], simv[2], simv[3]);
    *(float4*)&so[4] = make_float4(simv[4], simv[5], simv[6], simv[7]);

    float md = dist[0]; int mi = ent0;       // ascending strict < -> lowest j
    #pragma unroll
    for (int j = 1; j < 8; ++j)
      if (dist[j] < md) { md = dist[j]; mi = ent0 + j; }
    #pragma unroll
    for (int off = 1; off < 16; off <<= 1) { // reduce across 16-lane tx group
      float od = __shfl_xor(md, off);
      int   oi = __shfl_xor(mi, off);
      if (od < md || (od == md && oi < mi)) { md = od; mi = oi; }
    }
    if (tx == 0) pmin[tok * 4 + by] = make_float2(md, (float)mi);
  }
}

// ---------------- vq_finish: cross-partial argmin, z_q, ids, loss ---------
__global__ __launch_bounds__(256) void vq_finish_kernel(
    const float* __restrict__ ze, const float* __restrict__ cb,
    const float2* __restrict__ pmin, float* __restrict__ zq,
    float* __restrict__ ids_out, float* __restrict__ blocksum)
{
  const int tid = threadIdx.x;
  const int lane = tid & 63, wvid = tid >> 6;
  float lloss = 0.f;
  for (int it = 0; it < 16; ++it) {
    const int tok = blockIdx.x * 64 + wvid * 16 + it;
    float bd = 1e30f; int bi = 0;
    #pragma unroll
    for (int p = 0; p < 4; ++p) {            // 4 entry-tile partials, ascending
      float2 pr = pmin[tok * 4 + p];
      float d = pr.x; int i = (int)pr.y;
      if (d < bd || (d == bd && i < bi)) { bd = d; bi = i; }
    }
    float zev = ze[(size_t)tok * 64 + lane];
    float cv  = cb[(size_t)bi * 64 + lane];
    float df = zev - cv;
    float s = df * df;
    #pragma unroll
    for (int off = 32; off; off >>= 1) s += __shfl_down(s, off);
    zq[(size_t)tok * 64 + lane] = cv;
    if (lane == 0) { ids_out[tok] = (float)bi; lloss += sqrtf(s); }
  }
  __shared__ float ls[4];
  if (lane == 0) ls[wvid] = lloss;
  __syncthreads();
  if (tid == 0) blocksum[blockIdx.x] = ls[0] + ls[1] + ls[2] + ls[3];
}

__global__ void loss_fin_kernel(const float* __restrict__ blocksum,
                                float* __restrict__ out)
{
  const int lane = threadIdx.x;  // 64 threads
  float s = 0.f;
  for (int i = lane; i < 512; i += 64) s += blocksum[i];
  #pragma unroll
  for (int off = 32; off; off >>= 1) s += __shfl_down(s, off);
  if (lane == 0) out[0] = 1.25f * s / 32768.f;
}

// ---------------------------------------------------------------------------
#define LAUNCH_CONV3(DILV, RESV, XP, WP, BP, RP, YP)                           \
  do {                                                                         \
    if (T >= 32768)                                                            \
      conv3_kernel<DILV, RESV, 256><<<dim3(T / 256, 4), 512, 0, stream>>>(     \
          XP, WP, BP, RP, YP, T);                                              \
    else if (T >= 16384)                                                       \
      conv3_kernel<DILV, RESV, 128><<<dim3(T / 128, 4), 512, 0, stream>>>(     \
          XP, WP, BP, RP, YP, T);                                              \
    else                                                                       \
      conv3_kernel<DILV, RESV, 64><<<dim3(T / 64, 4), 512, 0, stream>>>(       \
          XP, WP, BP, RP, YP, T);                                              \
  } while (0)

extern "C" void kernel_launch(void* const* d_in, const int* in_sizes, int n_in,
                              void* d_out, int out_size, void* d_ws, size_t ws_size,
                              hipStream_t stream)
{
  const float* x       = (const float*)d_in[0];
  const float* w_down0 = (const float*)d_in[1];
  const float* b_down0 = (const float*)d_in[2];
  const float* w_down  = (const float*)d_in[3];
  const float* b_down  = (const float*)d_in[4];
  const float* w_res_e = (const float*)d_in[5];
  const float* b_res_e = (const float*)d_in[6];
  const float* cb      = (const float*)d_in[7];
  const float* w_res_d = (const float*)d_in[8];
  const float* b_res_d = (const float*)d_in[9];
  const float* w_up    = (const float*)d_in[10];
  const float* b_up    = (const float*)d_in[11];
  const float* w_proj  = (const float*)d_in[12];
  const float* b_proj  = (const float*)d_in[13];

  float* out = (float*)d_out;
  const size_t BUF = (size_t)4 * 65536 * 64;
  float*  bufA     = (float*)d_ws;
  float*  bufB     = bufA + BUF;
  float*  nzbuf    = bufB + BUF;
  float*  nebuf    = nzbuf + 32768;
  float2* pmin     = (float2*)(nebuf + 512);
  float*  blocksum = (float*)(pmin + 32768 * 4);

  float* h = bufA;
  float* tmp = bufB;

  // ---- encoder ----
  down0_kernel<<<32768, 256, 0, stream>>>(x, w_down0, b_down0, h);
  int T = 32768;
  for (int blk = 0; blk < 3; ++blk) {
    if (blk > 0) {
      down2_kernel<<<dim3(T / 2 / 64, 4), 512, 0, stream>>>(
          h, w_down + (size_t)(blk - 1) * 4 * 64 * 64, b_down + (blk - 1) * 64, tmp, T);
      T >>= 1;
      float* s = h; h = tmp; tmp = s;
    }
    for (int r = 0; r < 4; ++r) {
      const float* w0p = w_res_e + (((size_t)blk * 4 + r) * 2 + 0) * 3 * 64 * 64;
      const float* w1p = w_res_e + (((size_t)blk * 4 + r) * 2 + 1) * 3 * 64 * 64;
      const float* b0p = b_res_e + (((size_t)blk * 4 + r) * 2 + 0) * 64;
      const float* b1p = b_res_e + (((size_t)blk * 4 + r) * 2 + 1) * 64;
      LAUNCH_CONV3(3, false, h, w0p, b0p, nullptr, tmp);
      LAUNCH_CONV3(1, true,  tmp, w1p, b1p, h, h);
    }
  }

  // ---- VQ (T == 8192, z_e in h; 32768 tokens) ----
  nz_kernel<<<8192, 256, 0, stream>>>(h, nzbuf);
  ne_kernel<<<2, 256, 0, stream>>>(cb, nebuf);
  vq_dots_kernel<<<dim3(512, 4), 256, 0, stream>>>(h, cb, nzbuf, nebuf, out + OFF_SIM, pmin);
  vq_finish_kernel<<<512, 256, 0, stream>>>(h, cb, pmin, tmp, out + OFF_IDS, blocksum);
  loss_fin_kernel<<<1, 64, 0, stream>>>(blocksum, out + OFF_LOSS);
  { float* s = h; h = tmp; tmp = s; }  // h = z_q

  // ---- decoder ----
  for (int blk = 0; blk < 3; ++blk) {
    for (int r = 0; r < 4; ++r) {
      const float* w0p = w_res_d + (((size_t)blk * 4 + r) * 2 + 0) * 3 * 64 * 64;
      const float* w1p = w_res_d + (((size_t)blk * 4 + r) * 2 + 1) * 3 * 64 * 64;
      const float* b0p = b_res_d + (((size_t)blk * 4 + r) * 2 + 0) * 64;
      const float* b1p = b_res_d + (((size_t)blk * 4 + r) * 2 + 1) * 64;
      LAUNCH_CONV3(1, false, h, w0p, b0p, nullptr, tmp);
      LAUNCH_CONV3(3, true,  tmp, w1p, b1p, h, h);
    }
    up_kernel<<<dim3(2 * T / 128, 4), 512, 0, stream>>>(
        h, w_up + (size_t)blk * 4 * 64 * 64, b_up + blk * 64, tmp, T);
    T <<= 1;
    float* s = h; h = tmp; tmp = s;
  }

  // ---- final projection (T == 65536) ----
  proj_kernel<<<1024, 256, 0, stream>>>(h, w_proj, b_proj, out);
}

// Round 9
// 1753.900 us; speedup vs baseline: 1.1626x; 1.0133x over previous
//
#include <hip/hip_runtime.h>
#include <cstdint>

// ---------------------------------------------------------------------------
// JukeboxAutoEncoder fp32, round 16.
// r15 post-mortem: ci-split reassociated the channel sum -> z_e 1-ulp shift
//   -> argmin tie flips -> ids FAIL. conv accumulation order is FROZEN.
// This round: fused residual-pair kernel (conv dilA -> LDS -> conv dilB ->
//   +res from staged x), bit-exact vs r10 (same fmaf nest, same ci order,
//   same zero-padding semantics incl. interm OOB = 0). Saves per pair: interm
//   HBM write+read, res global read, one staging pass, one dispatch.
//   TT = 64-2*DILB so interm tile = 64 = one lane each (no masked tail).
//   LDS 36.9KB (xs swizzled + is_ natural) -> 4 blocks/CU, (512,8).
// Output layout (flat f32): x_hat[262144] | loss_vq[1] | ids[32768] | sim[16777216]
// ---------------------------------------------------------------------------

#define OFF_LOSS 262144
#define OFF_IDS  262145
#define OFF_SIM  294913

// ---------------- down0: (B,65536,1) -> (B,32768,64), K=4 stride2, relu ----
__global__ __launch_bounds__(256) void down0_kernel(
    const float* __restrict__ x, const float* __restrict__ w,
    const float* __restrict__ bias, float* __restrict__ y)
{
  int idx = blockIdx.x * 256 + threadIdx.x;   // enumerates (b, t, co)
  int co = idx & 63;
  int r  = idx >> 6;
  int t  = r & 32767;
  int b  = r >> 15;
  const float* xb = x + (size_t)b * 65536;
  float acc = bias[co];
  #pragma unroll
  for (int k = 0; k < 4; ++k) {
    int gt = 2 * t - 1 + k;
    float xv = ((unsigned)gt < 65536u) ? xb[gt] : 0.f;
    acc += xv * w[k * 64 + co];
  }
  y[(size_t)idx] = fmaxf(acc, 0.f);
}

// ---------------- fused residual pair: relu(convB(relu(convA(x)))) + x ----
// grid (ceil(T/TT), 4), 512 thr = 8 waves; wave wv owns co0 = wv*8
// (wave-uniform -> s_load weights, exactly r10's inner loop twice).
// interm position per lane (64 = TT + 2*DILB); x tile XT = 64 + 2*DILA.
template <int DILA, int DILB>
__global__ __launch_bounds__(512, 8) void resblock_kernel(
    const float* __restrict__ x, const float* __restrict__ wa,
    const float* __restrict__ ba, const float* __restrict__ wb,
    const float* __restrict__ bbv, float* __restrict__ y, int T)
{
  constexpr int H  = DILA + DILB;            // 4
  constexpr int TT = 64 - 2 * DILB;          // 62 (enc) / 58 (dec)
  constexpr int XT = 64 + 2 * DILA;          // 70 / 66
  constexpr int XS = 80;                     // swizzle-safe row stride
  __shared__ float xs[64 * XS];              // 20.5 KB, [ci][t] swizzled
  __shared__ float is_[64 * 64 + 16];        // 16 KB interm, natural layout
  const int tid  = threadIdx.x;
  const int lane = tid & 63;
  const int b    = blockIdx.y;
  const int t0   = blockIdx.x * TT;
  const int wv   = __builtin_amdgcn_readfirstlane(tid >> 6);
  const int co0  = __builtin_amdgcn_readfirstlane(wv * 8);

  // stage x[t0-H .. t0-H+XT) x 64ci, transposed, swizzled (r10 scheme)
  const float* xb = x + (size_t)b * T * 64;
  for (int e = tid; e < 16 * XT; e += 512) {
    int tl = e >> 4, cq = (e & 15) * 4;
    int cs = tl ^ (((cq >> 2) & 7) << 1);
    int gt = t0 - H + tl;
    float4 v = make_float4(0.f, 0.f, 0.f, 0.f);
    if ((unsigned)gt < (unsigned)T) v = *(const float4*)&xb[(size_t)gt * 64 + cq];
    xs[(cq + 0) * XS + cs] = v.x;
    xs[(cq + 1) * XS + cs] = v.y;
    xs[(cq + 2) * XS + cs] = v.z;
    xs[(cq + 3) * XS + cs] = v.w;
  }
  __syncthreads();

  // ---- conv A: interm pos it = lane, global t' = t0 - DILB + it ----------
  {
    const int it = lane;
    float acc[8] = {};
    const float* wba = wa + co0;
    for (int ci = 0; ci < 64; ++ci) {
      const int swz = ((ci >> 2) & 7) << 1;
      const float* xr = xs + ci * XS;
      float x0 = xr[(it) ^ swz];             // x[t'-A]
      float x1 = xr[(it + DILA) ^ swz];      // x[t']
      float x2 = xr[(it + 2 * DILA) ^ swz];  // x[t'+A]
      const float* w0 = wba + (0 * 64 + ci) * 64;
      const float* w1 = wba + (1 * 64 + ci) * 64;
      const float* w2 = wba + (2 * 64 + ci) * 64;
      #pragma unroll
      for (int j = 0; j < 8; ++j)
        acc[j] = fmaf(x0, w0[j], fmaf(x1, w1[j], fmaf(x2, w2[j], acc[j])));
    }
    const bool valid = (unsigned)(t0 - DILB + it) < (unsigned)T;  // SAME pad
    #pragma unroll
    for (int j = 0; j < 8; ++j)
      is_[(co0 + j) * 64 + it] = valid ? fmaxf(acc[j] + ba[co0 + j], 0.f) : 0.f;
  }
  __syncthreads();

  // ---- conv B + res + write: output t = t0 + lane (lane < TT) ------------
  {
    float acc[8] = {};
    const float* wbb = wb + co0;
    for (int ci = 0; ci < 64; ++ci) {
      const float* ir = is_ + ci * 64;
      float v0 = ir[lane];                   // interm[t-B]
      float v1 = ir[lane + DILB];            // interm[t]
      float v2 = ir[lane + 2 * DILB];        // interm[t+B]
      const float* w0 = wbb + (0 * 64 + ci) * 64;
      const float* w1 = wbb + (1 * 64 + ci) * 64;
      const float* w2 = wbb + (2 * 64 + ci) * 64;
      #pragma unroll
      for (int j = 0; j < 8; ++j)
        acc[j] = fmaf(v0, w0[j], fmaf(v1, w1[j], fmaf(v2, w2[j], acc[j])));
    }
    if (lane < TT && (unsigned)(t0 + lane) < (unsigned)T) {
      float r[8];
      #pragma unroll
      for (int j = 0; j < 8; ++j) {
        const int row = co0 + j;
        const int swzj = ((row >> 2) & 7) << 1;
        float xres = xs[row * XS + ((lane + H) ^ swzj)];   // original x at t
        r[j] = fmaxf(acc[j] + bbv[row], 0.f) + xres;
      }
      size_t o = ((size_t)b * T + t0 + lane) * 64 + co0;
      *(float4*)&y[o]     = make_float4(r[0], r[1], r[2], r[3]);
      *(float4*)&y[o + 4] = make_float4(r[4], r[5], r[6], r[7]);
    }
  }
}

// ---------------- down2: K=4 stride2, 64->64, relu (r10) ------------------
__global__ __launch_bounds__(512, 8) void down2_kernel(
    const float* __restrict__ x, const float* __restrict__ w,
    const float* __restrict__ bias, float* __restrict__ y, int Tin)
{
  constexpr int XT = 130, XS = 144;          // swizzle-safe stride
  __shared__ float xs[64 * XS];
  const int tid  = threadIdx.x;
  const int lane = tid & 63;
  const int b    = blockIdx.y;
  const int t0   = blockIdx.x * 64;
  const int Tout = Tin >> 1;
  const int wv   = __builtin_amdgcn_readfirstlane(tid >> 6);
  const int co0  = __builtin_amdgcn_readfirstlane(wv * 8);

  const float* xb = x + (size_t)b * Tin * 64;
  for (int e = tid; e < 16 * XT; e += 512) {
    int tl = e >> 4, cq = (e & 15) * 4;
    int cs = tl ^ (((cq >> 2) & 7) << 1);
    int gt = 2 * t0 - 1 + tl;
    float4 v = make_float4(0.f, 0.f, 0.f, 0.f);
    if ((unsigned)gt < (unsigned)Tin) v = *(const float4*)&xb[(size_t)gt * 64 + cq];
    xs[(cq + 0) * XS + cs] = v.x;
    xs[(cq + 1) * XS + cs] = v.y;
    xs[(cq + 2) * XS + cs] = v.z;
    xs[(cq + 3) * XS + cs] = v.w;
  }
  __syncthreads();

  float acc[8] = {};
  const float* wb = w + co0;
  for (int ci = 0; ci < 64; ++ci) {
    const int swz = ((ci >> 2) & 7) << 1;
    const float* xr = xs + ci * XS;
    float2 v0 = *(const float2*)&xr[(2 * lane) ^ swz];
    float2 v1 = *(const float2*)&xr[(2 * lane + 2) ^ swz];
    float a0 = v0.x, a1 = v0.y, a2 = v1.x, a3 = v1.y;
    const float* w0 = wb + (0 * 64 + ci) * 64;
    const float* w1 = wb + (1 * 64 + ci) * 64;
    const float* w2 = wb + (2 * 64 + ci) * 64;
    const float* w3 = wb + (3 * 64 + ci) * 64;
    #pragma unroll
    for (int j = 0; j < 8; ++j)
      acc[j] = fmaf(a0, w0[j], fmaf(a1, w1[j], fmaf(a2, w2[j], fmaf(a3, w3[j], acc[j]))));
  }

  size_t o = ((size_t)b * Tout + t0 + lane) * 64 + co0;
  #pragma unroll
  for (int q = 0; q < 2; ++q) {
    float4 rr;
    rr.x = fmaxf(acc[4*q+0] + bias[co0 + 4*q+0], 0.f);
    rr.y = fmaxf(acc[4*q+1] + bias[co0 + 4*q+1], 0.f);
    rr.z = fmaxf(acc[4*q+2] + bias[co0 + 4*q+2], 0.f);
    rr.w = fmaxf(acc[4*q+3] + bias[co0 + 4*q+3], 0.f);
    *(float4*)&y[o + 4 * q] = rr;
  }
}

// ---------------- up: conv_transpose K=4 stride2, 64->64, relu (r10) ------
__global__ __launch_bounds__(512, 8) void up_kernel(
    const float* __restrict__ x, const float* __restrict__ w,
    const float* __restrict__ bias, float* __restrict__ y, int Tin)
{
  constexpr int XT = 66, XS = 80;            // swizzle-safe stride
  __shared__ float xs[64 * XS];
  const int tid  = threadIdx.x;
  const int lane = tid & 63;
  const int b    = blockIdx.y;
  const int u0   = blockIdx.x * 64;
  const int Tout = Tin << 1;
  const int wv   = __builtin_amdgcn_readfirstlane(tid >> 6);
  const int co0  = __builtin_amdgcn_readfirstlane(wv * 8);

  const float* xb = x + (size_t)b * Tin * 64;
  for (int e = tid; e < 16 * XT; e += 512) {
    int ul = e >> 4, cq = (e & 15) * 4;
    int cs = ul ^ (((cq >> 2) & 7) << 1);
    int gu = u0 - 1 + ul;
    float4 v = make_float4(0.f, 0.f, 0.f, 0.f);
    if ((unsigned)gu < (unsigned)Tin) v = *(const float4*)&xb[(size_t)gu * 64 + cq];
    xs[(cq + 0) * XS + cs] = v.x;
    xs[(cq + 1) * XS + cs] = v.y;
    xs[(cq + 2) * XS + cs] = v.z;
    xs[(cq + 3) * XS + cs] = v.w;
  }
  __syncthreads();

  float acce[8] = {}, acco[8] = {};
  const float* wb = w + co0;
  for (int ci = 0; ci < 64; ++ci) {
    const int swz = ((ci >> 2) & 7) << 1;
    const float* xr = xs + ci * XS;
    float a0 = xr[(lane) ^ swz];             // x[u-1]
    float a1 = xr[(lane + 1) ^ swz];         // x[u]
    float a2 = xr[(lane + 2) ^ swz];         // x[u+1]
    const float* w0 = wb + (0 * 64 + ci) * 64;
    const float* w1 = wb + (1 * 64 + ci) * 64;
    const float* w2 = wb + (2 * 64 + ci) * 64;
    const float* w3 = wb + (3 * 64 + ci) * 64;
    #pragma unroll
    for (int j = 0; j < 8; ++j) {
      acce[j] = fmaf(a0, w0[j], fmaf(a1, w2[j], acce[j]));
      acco[j] = fmaf(a1, w1[j], fmaf(a2, w3[j], acco[j]));
    }
  }

  size_t oe = ((size_t)b * Tout + 2 * (u0 + lane)) * 64 + co0;
  size_t oo = oe + 64;
  #pragma unroll
  for (int q = 0; q < 2; ++q) {
    float4 re, ro;
    re.x = fmaxf(acce[4*q+0] + bias[co0 + 4*q+0], 0.f);
    re.y = fmaxf(acce[4*q+1] + bias[co0 + 4*q+1], 0.f);
    re.z = fmaxf(acce[4*q+2] + bias[co0 + 4*q+2], 0.f);
    re.w = fmaxf(acce[4*q+3] + bias[co0 + 4*q+3], 0.f);
    ro.x = fmaxf(acco[4*q+0] + bias[co0 + 4*q+0], 0.f);
    ro.y = fmaxf(acco[4*q+1] + bias[co0 + 4*q+1], 0.f);
    ro.z = fmaxf(acco[4*q+2] + bias[co0 + 4*q+2], 0.f);
    ro.w = fmaxf(acco[4*q+3] + bias[co0 + 4*q+3], 0.f);
    *(float4*)&y[oe + 4 * q] = re;
    *(float4*)&y[oo + 4 * q] = ro;
  }
}

// ---------------- proj: K=3 dil1, 64->1, linear ---------------------------
__global__ __launch_bounds__(256) void proj_kernel(
    const float* __restrict__ x, const float* __restrict__ w,
    const float* __restrict__ bias, float* __restrict__ out)
{
  const int lane = threadIdx.x & 63;
  const int wid  = (blockIdx.x * 256 + threadIdx.x) >> 6;  // 4096 waves
  const float w0 = w[lane], w1 = w[64 + lane], w2 = w[128 + lane];
  const float bb = bias[0];
  size_t base = (size_t)wid * 64;
  for (int i = 0; i < 64; ++i) {
    size_t tau = base + i;
    int b = (int)(tau >> 16);
    int t = (int)(tau & 65535);
    const float* xb = x + ((size_t)b * 65536) * 64;
    float pm = (t > 0)     ? xb[(size_t)(t - 1) * 64 + lane] : 0.f;
    float pc =               xb[(size_t)t * 64 + lane];
    float pp = (t < 65535) ? xb[(size_t)(t + 1) * 64 + lane] : 0.f;
    float s = pm * w0 + pc * w1 + pp * w2;
    #pragma unroll
    for (int off = 32; off; off >>= 1) s += __shfl_down(s, off);
    if (lane == 0) out[tau] = s + bb;
  }
}

// ---------------- nz: per-token sum of squares ----------------------------
__global__ __launch_bounds__(256) void nz_kernel(
    const float* __restrict__ ze, float* __restrict__ nz)
{
  int lane = threadIdx.x & 63;
  int tok  = (blockIdx.x * 256 + threadIdx.x) >> 6;
  float v = ze[(size_t)tok * 64 + lane];
  float s = v * v;
  #pragma unroll
  for (int off = 32; off; off >>= 1) s += __shfl_down(s, off);
  if (lane == 0) nz[tok] = s;
}

// ---------------- ne: per-entry codebook norm (512 entries, once) ---------
__global__ __launch_bounds__(256) void ne_kernel(
    const float* __restrict__ cb, float* __restrict__ ne)
{
  int c = blockIdx.x * 256 + threadIdx.x;   // grid 2 -> 512 entries
  const float4* p = (const float4*)(cb + (size_t)c * 64);
  float s = 0.f;
  #pragma unroll
  for (int q = 0; q < 16; ++q) {
    float4 v = p[q];
    s += v.x * v.x + v.y * v.y + v.z * v.z + v.w * v.w;
  }
  ne[c] = s;
}

// ---------------- vq_dots: register-blocked GEMM --------------------------
__global__ __launch_bounds__(256) void vq_dots_kernel(
    const float* __restrict__ ze, const float* __restrict__ cb,
    const float* __restrict__ nzbuf, const float* __restrict__ nebuf,
    float* __restrict__ sim_out, float2* __restrict__ pmin)
{
  constexpr int ZS = 68, CS = 132;
  __shared__ float zt[64 * ZS];              // [d][tok]   17.4 KB
  __shared__ float ct[64 * CS];              // [d][ent]   33.8 KB
  const int tid = threadIdx.x;
  const int tx  = tid & 15;                  // entry group (8 entries)
  const int ty  = tid >> 4;                  // token group (4 tokens)
  const int bx  = blockIdx.x, by = blockIdx.y;

  {                                          // stage z tile (transpose, swz)
    const float* zb = ze + (size_t)bx * 64 * 64;
    #pragma unroll
    for (int it = 0; it < 4; ++it) {
      int e = tid + it * 256;
      int tl = e >> 4, cq = (e & 15) * 4;
      int cs = tl ^ (((cq >> 2) & 7) << 2);
      float4 v = *(const float4*)&zb[tl * 64 + cq];
      zt[(cq + 0) * ZS + cs] = v.x;
      zt[(cq + 1) * ZS + cs] = v.y;
      zt[(cq + 2) * ZS + cs] = v.z;
      zt[(cq + 3) * ZS + cs] = v.w;
    }
    const float* cbb = cb + (size_t)by * 128 * 64;
    #pragma unroll
    for (int it = 0; it < 8; ++it) {
      int e = tid + it * 256;
      int el = e >> 4, cq = (e & 15) * 4;
      int cs = el ^ (((cq >> 2) & 7) << 2);
      float4 v = *(const float4*)&cbb[el * 64 + cq];
      ct[(cq + 0) * CS + cs] = v.x;
      ct[(cq + 1) * CS + cs] = v.y;
      ct[(cq + 2) * CS + cs] = v.z;
      ct[(cq + 3) * CS + cs] = v.w;
    }
  }
  __syncthreads();

  float acc[4][8] = {};
  #pragma unroll 4
  for (int k = 0; k < 64; ++k) {
    const int swz = ((k >> 2) & 7) << 2;
    float4 zv = *(const float4*)&zt[k * ZS + ((ty * 4) ^ swz)];
    float4 c0 = *(const float4*)&ct[k * CS + ((tx * 8) ^ swz)];
    float4 c1 = *(const float4*)&ct[k * CS + ((tx * 8 + 4) ^ swz)];
    float zr[4] = {zv.x, zv.y, zv.z, zv.w};
    float cr[8] = {c0.x, c0.y, c0.z, c0.w, c1.x, c1.y, c1.z, c1.w};
    #pragma unroll
    for (int i = 0; i < 4; ++i)
      #pragma unroll
      for (int j = 0; j < 8; ++j)
        acc[i][j] = fmaf(zr[i], cr[j], acc[i][j]);
  }

  // epilogue: dist, sim, argmin partials
  float4 nzq = *(const float4*)&nzbuf[bx * 64 + ty * 4];
  float nzv[4] = {nzq.x, nzq.y, nzq.z, nzq.w};
  float4 ne0  = *(const float4*)&nebuf[by * 128 + tx * 8];
  float4 ne1  = *(const float4*)&nebuf[by * 128 + tx * 8 + 4];
  float nev[8]  = {ne0.x, ne0.y, ne0.z, ne0.w, ne1.x, ne1.y, ne1.z, ne1.w};
  float rsne[8];
  #pragma unroll
  for (int j = 0; j < 8; ++j) rsne[j] = 1.f / sqrtf(nev[j]);
  const int ent0 = by * 128 + tx * 8;

  #pragma unroll
  for (int i = 0; i < 4; ++i) {
    const int tok = bx * 64 + ty * 4 + i;
    const float rsnz = 1.f / sqrtf(nzv[i]);
    float dist[8], simv[8];
    #pragma unroll
    for (int j = 0; j < 8; ++j) {
      dist[j] = (-2.f * acc[i][j] + nzv[i]) + nev[j];
      simv[j] = acc[i][j] * rsnz * rsne[j];
    }
    float* so = sim_out + (size_t)tok * 512 + ent0;
    *(float4*)&so[0] = make_float4(simv[0], simv[1], simv[2], simv[3]);
    *(float4*)&so[4] = make_float4(simv[4], simv[5], simv[6], simv[7]);

    float md = dist[0]; int mi = ent0;       // ascending strict < -> lowest j
    #pragma unroll
    for (int j = 1; j < 8; ++j)
      if (dist[j] < md) { md = dist[j]; mi = ent0 + j; }
    #pragma unroll
    for (int off = 1; off < 16; off <<= 1) { // reduce across 16-lane tx group
      float od = __shfl_xor(md, off);
      int   oi = __shfl_xor(mi, off);
      if (od < md || (od == md && oi < mi)) { md = od; mi = oi; }
    }
    if (tx == 0) pmin[tok * 4 + by] = make_float2(md, (float)mi);
  }
}

// ---------------- vq_finish: cross-partial argmin, z_q, ids, loss ---------
__global__ __launch_bounds__(256) void vq_finish_kernel(
    const float* __restrict__ ze, const float* __restrict__ cb,
    const float2* __restrict__ pmin, float* __restrict__ zq,
    float* __restrict__ ids_out, float* __restrict__ blocksum)
{
  const int tid = threadIdx.x;
  const int lane = tid & 63, wvid = tid >> 6;
  float lloss = 0.f;
  for (int it = 0; it < 16; ++it) {
    const int tok = blockIdx.x * 64 + wvid * 16 + it;
    float bd = 1e30f; int bi = 0;
    #pragma unroll
    for (int p = 0; p < 4; ++p) {            // 4 entry-tile partials, ascending
      float2 pr = pmin[tok * 4 + p];
      float d = pr.x; int i = (int)pr.y;
      if (d < bd || (d == bd && i < bi)) { bd = d; bi = i; }
    }
    float zev = ze[(size_t)tok * 64 + lane];
    float cv  = cb[(size_t)bi * 64 + lane];
    float df = zev - cv;
    float s = df * df;
    #pragma unroll
    for (int off = 32; off; off >>= 1) s += __shfl_down(s, off);
    zq[(size_t)tok * 64 + lane] = cv;
    if (lane == 0) { ids_out[tok] = (float)bi; lloss += sqrtf(s); }
  }
  __shared__ float ls[4];
  if (lane == 0) ls[wvid] = lloss;
  __syncthreads();
  if (tid == 0) blocksum[blockIdx.x] = ls[0] + ls[1] + ls[2] + ls[3];
}

__global__ void loss_fin_kernel(const float* __restrict__ blocksum,
                                float* __restrict__ out)
{
  const int lane = threadIdx.x;  // 64 threads
  float s = 0.f;
  for (int i = lane; i < 512; i += 64) s += blocksum[i];
  #pragma unroll
  for (int off = 32; off; off >>= 1) s += __shfl_down(s, off);
  if (lane == 0) out[0] = 1.25f * s / 32768.f;
}

// ---------------------------------------------------------------------------
extern "C" void kernel_launch(void* const* d_in, const int* in_sizes, int n_in,
                              void* d_out, int out_size, void* d_ws, size_t ws_size,
                              hipStream_t stream)
{
  const float* x       = (const float*)d_in[0];
  const float* w_down0 = (const float*)d_in[1];
  const float* b_down0 = (const float*)d_in[2];
  const float* w_down  = (const float*)d_in[3];
  const float* b_down  = (const float*)d_in[4];
  const float* w_res_e = (const float*)d_in[5];
  const float* b_res_e = (const float*)d_in[6];
  const float* cb      = (const float*)d_in[7];
  const float* w_res_d = (const float*)d_in[8];
  const float* b_res_d = (const float*)d_in[9];
  const float* w_up    = (const float*)d_in[10];
  const float* b_up    = (const float*)d_in[11];
  const float* w_proj  = (const float*)d_in[12];
  const float* b_proj  = (const float*)d_in[13];

  float* out = (float*)d_out;
  const size_t BUF = (size_t)4 * 65536 * 64;
  float*  bufA     = (float*)d_ws;
  float*  bufB     = bufA + BUF;
  float*  nzbuf    = bufB + BUF;
  float*  nebuf    = nzbuf + 32768;
  float2* pmin     = (float2*)(nebuf + 512);
  float*  blocksum = (float*)(pmin + 32768 * 4);

  float* h = bufA;
  float* tmp = bufB;

  // ---- encoder ----
  down0_kernel<<<32768, 256, 0, stream>>>(x, w_down0, b_down0, h);
  int T = 32768;
  for (int blk = 0; blk < 3; ++blk) {
    if (blk > 0) {
      down2_kernel<<<dim3(T / 2 / 64, 4), 512, 0, stream>>>(
          h, w_down + (size_t)(blk - 1) * 4 * 64 * 64, b_down + (blk - 1) * 64, tmp, T);
      T >>= 1;
      float* s = h; h = tmp; tmp = s;
    }
    for (int r = 0; r < 4; ++r) {
      const float* w0p = w_res_e + (((size_t)blk * 4 + r) * 2 + 0) * 3 * 64 * 64;
      const float* w1p = w_res_e + (((size_t)blk * 4 + r) * 2 + 1) * 3 * 64 * 64;
      const float* b0p = b_res_e + (((size_t)blk * 4 + r) * 2 + 0) * 64;
      const float* b1p = b_res_e + (((size_t)blk * 4 + r) * 2 + 1) * 64;
      // fused: relu(conv_d1(relu(conv_d3(h)))) + h -> tmp   (TT = 62)
      resblock_kernel<3, 1><<<dim3((T + 61) / 62, 4), 512, 0, stream>>>(
          h, w0p, b0p, w1p, b1p, tmp, T);
      float* s = h; h = tmp; tmp = s;
    }
  }

  // ---- VQ (T == 8192, z_e in h; 32768 tokens) ----
  nz_kernel<<<8192, 256, 0, stream>>>(h, nzbuf);
  ne_kernel<<<2, 256, 0, stream>>>(cb, nebuf);
  vq_dots_kernel<<<dim3(512, 4), 256, 0, stream>>>(h, cb, nzbuf, nebuf, out + OFF_SIM, pmin);
  vq_finish_kernel<<<512, 256, 0, stream>>>(h, cb, pmin, tmp, out + OFF_IDS, blocksum);
  loss_fin_kernel<<<1, 64, 0, stream>>>(blocksum, out + OFF_LOSS);
  { float* s = h; h = tmp; tmp = s; }  // h = z_q

  // ---- decoder ----
  for (int blk = 0; blk < 3; ++blk) {
    for (int r = 0; r < 4; ++r) {
      const float* w0p = w_res_d + (((size_t)blk * 4 + r) * 2 + 0) * 3 * 64 * 64;
      const float* w1p = w_res_d + (((size_t)blk * 4 + r) * 2 + 1) * 3 * 64 * 64;
      const float* b0p = b_res_d + (((size_t)blk * 4 + r) * 2 + 0) * 64;
      const float* b1p = b_res_d + (((size_t)blk * 4 + r) * 2 + 1) * 64;
      // fused: relu(conv_d3(relu(conv_d1(h)))) + h -> tmp   (TT = 58)
      resblock_kernel<1, 3><<<dim3((T + 57) / 58, 4), 512, 0, stream>>>(
          h, w0p, b0p, w1p, b1p, tmp, T);
      float* s = h; h = tmp; tmp = s;
    }
    up_kernel<<<dim3(2 * T / 128, 4), 512, 0, stream>>>(
        h, w_up + (size_t)blk * 4 * 64 * 64, b_up + blk * 64, tmp, T);
    T <<= 1;
    float* s = h; h = tmp; tmp = s;
  }

  // ---- final projection (T == 65536) ----
  proj_kernel<<<1024, 256, 0, stream>>>(h, w_proj, b_proj, out);
}

// Round 10
// 1725.871 us; speedup vs baseline: 1.1815x; 1.0162x over previous
//
#include <hip/hip_runtime.h>
#include <cstdint>

// ---------------------------------------------------------------------------
// JukeboxAutoEncoder fp32, round 17.
// r16 post-mortem: residual-pair fusion halved HBM (never the bottleneck) but
//   halved the per-phase t-tile -> staging overhead per FMA doubled -> net
//   -148us. Reverted to r10 wholesale (best verified 1606us).
// This round: up_kernel TPL=1 -> TPL=2 (128 u/block, down2's staging geometry
//   XT=130/XS=144). Doubles FMA per lgkmcnt drain (up was the worst
//   floor-ratio kernel: 72us vs 27us floor @T=65536, FMA duty 37%). Per-output
//   accumulation chain bit-identical (same taps, same fmaf nest, ci order).
//   LDS 36.9KB -> 4 blocks/CU = 32 waves (unchanged occupancy).
// Output layout (flat f32): x_hat[262144] | loss_vq[1] | ids[32768] | sim[16777216]
// ---------------------------------------------------------------------------

#define OFF_LOSS 262144
#define OFF_IDS  262145
#define OFF_SIM  294913

// ---------------- down0: (B,65536,1) -> (B,32768,64), K=4 stride2, relu ----
__global__ __launch_bounds__(256) void down0_kernel(
    const float* __restrict__ x, const float* __restrict__ w,
    const float* __restrict__ bias, float* __restrict__ y)
{
  int idx = blockIdx.x * 256 + threadIdx.x;   // enumerates (b, t, co)
  int co = idx & 63;
  int r  = idx >> 6;
  int t  = r & 32767;
  int b  = r >> 15;
  const float* xb = x + (size_t)b * 65536;
  float acc = bias[co];
  #pragma unroll
  for (int k = 0; k < 4; ++k) {
    int gt = 2 * t - 1 + k;
    float xv = ((unsigned)gt < 65536u) ? xb[gt] : 0.f;
    acc += xv * w[k * 64 + co];
  }
  y[(size_t)idx] = fmaxf(acc, 0.f);
}

// ---------------- conv3: K=3, dil DIL, 64->64, relu, optional +res --------
// (r10 version) 512 thr = 8 waves; wave wv owns co0 = wv*8.
template <int DIL, bool HAS_RES, int TT>
__global__ __launch_bounds__(512, 8) void conv3_kernel(
    const float* __restrict__ x, const float* __restrict__ w,
    const float* __restrict__ bias, const float* res,
    float* y, int T)
{
  constexpr int TPL = TT / 64;               // 1 or 2 t per lane
  constexpr int XT  = TT + 2 * DIL;
  constexpr int XS  = ((XT - 1) | 15) + 1;   // swizzle-safe row stride
  constexpr int NV  = TPL + 2 * DIL;
  __shared__ float xs[64 * XS];
  const int tid  = threadIdx.x;
  const int lane = tid & 63;
  const int b    = blockIdx.y;
  const int t0   = blockIdx.x * TT;
  const int wv   = __builtin_amdgcn_readfirstlane(tid >> 6);
  const int co0  = __builtin_amdgcn_readfirstlane(wv * 8);

  const float* xb = x + (size_t)b * T * 64;
  for (int e = tid; e < 16 * XT; e += 512) { // transpose to [ci][t], swizzled
    int tl = e >> 4, cq = (e & 15) * 4;
    int cs = tl ^ (((cq >> 2) & 7) << 1);    // rows cq..cq+3 share cq>>2
    int gt = t0 - DIL + tl;
    float4 v = make_float4(0.f, 0.f, 0.f, 0.f);
    if ((unsigned)gt < (unsigned)T) v = *(const float4*)&xb[(size_t)gt * 64 + cq];
    xs[(cq + 0) * XS + cs] = v.x;
    xs[(cq + 1) * XS + cs] = v.y;
    xs[(cq + 2) * XS + cs] = v.z;
    xs[(cq + 3) * XS + cs] = v.w;
  }
  __syncthreads();

  float acc[TPL][8] = {};
  const float* wb = w + co0;                 // w[k][ci][co0..co0+7]
  const int tb = TPL * lane;
  for (int ci = 0; ci < 64; ++ci) {
    const int swz = ((ci >> 2) & 7) << 1;
    const float* xr = xs + ci * XS;
    float xv[NV];
    if constexpr (TPL == 2) {                // 8B-aligned -> ds_read_b64
      #pragma unroll
      for (int q = 0; q < NV / 2; ++q) {
        float2 v = *(const float2*)&xr[(tb + 2 * q) ^ swz];
        xv[2*q] = v.x; xv[2*q+1] = v.y;
      }
    } else {
      #pragma unroll
      for (int j = 0; j < NV; ++j) xv[j] = xr[(tb + j) ^ swz];
    }
    const float* w0 = wb + (0 * 64 + ci) * 64;
    const float* w1 = wb + (1 * 64 + ci) * 64;
    const float* w2 = wb + (2 * 64 + ci) * 64;
    #pragma unroll
    for (int j = 0; j < 8; ++j) {
      float c0 = w0[j], c1 = w1[j], c2 = w2[j];
      #pragma unroll
      for (int i = 0; i < TPL; ++i)
        acc[i][j] = fmaf(xv[i], c0, fmaf(xv[i + DIL], c1, fmaf(xv[i + 2 * DIL], c2, acc[i][j])));
    }
  }

  float bs[8];
  #pragma unroll
  for (int j = 0; j < 8; ++j) bs[j] = bias[co0 + j];
  #pragma unroll
  for (int i = 0; i < TPL; ++i) {
    size_t o = ((size_t)b * T + t0 + tb + i) * 64 + co0;
    float r[8];
    #pragma unroll
    for (int j = 0; j < 8; ++j) r[j] = fmaxf(acc[i][j] + bs[j], 0.f);
    if (HAS_RES) {
      float4 v0 = *(const float4*)&res[o];
      float4 v1 = *(const float4*)&res[o + 4];
      r[0] += v0.x; r[1] += v0.y; r[2] += v0.z; r[3] += v0.w;
      r[4] += v1.x; r[5] += v1.y; r[6] += v1.z; r[7] += v1.w;
    }
    *(float4*)&y[o]     = make_float4(r[0], r[1], r[2], r[3]);
    *(float4*)&y[o + 4] = make_float4(r[4], r[5], r[6], r[7]);
  }
}

// ---------------- down2: K=4 stride2, 64->64, relu (r10) ------------------
__global__ __launch_bounds__(512, 8) void down2_kernel(
    const float* __restrict__ x, const float* __restrict__ w,
    const float* __restrict__ bias, float* __restrict__ y, int Tin)
{
  constexpr int XT = 130, XS = 144;          // swizzle-safe stride
  __shared__ float xs[64 * XS];
  const int tid  = threadIdx.x;
  const int lane = tid & 63;
  const int b    = blockIdx.y;
  const int t0   = blockIdx.x * 64;
  const int Tout = Tin >> 1;
  const int wv   = __builtin_amdgcn_readfirstlane(tid >> 6);
  const int co0  = __builtin_amdgcn_readfirstlane(wv * 8);

  const float* xb = x + (size_t)b * Tin * 64;
  for (int e = tid; e < 16 * XT; e += 512) {
    int tl = e >> 4, cq = (e & 15) * 4;
    int cs = tl ^ (((cq >> 2) & 7) << 1);
    int gt = 2 * t0 - 1 + tl;
    float4 v = make_float4(0.f, 0.f, 0.f, 0.f);
    if ((unsigned)gt < (unsigned)Tin) v = *(const float4*)&xb[(size_t)gt * 64 + cq];
    xs[(cq + 0) * XS + cs] = v.x;
    xs[(cq + 1) * XS + cs] = v.y;
    xs[(cq + 2) * XS + cs] = v.z;
    xs[(cq + 3) * XS + cs] = v.w;
  }
  __syncthreads();

  float acc[8] = {};
  const float* wb = w + co0;
  for (int ci = 0; ci < 64; ++ci) {
    const int swz = ((ci >> 2) & 7) << 1;
    const float* xr = xs + ci * XS;
    float2 v0 = *(const float2*)&xr[(2 * lane) ^ swz];
    float2 v1 = *(const float2*)&xr[(2 * lane + 2) ^ swz];
    float a0 = v0.x, a1 = v0.y, a2 = v1.x, a3 = v1.y;
    const float* w0 = wb + (0 * 64 + ci) * 64;
    const float* w1 = wb + (1 * 64 + ci) * 64;
    const float* w2 = wb + (2 * 64 + ci) * 64;
    const float* w3 = wb + (3 * 64 + ci) * 64;
    #pragma unroll
    for (int j = 0; j < 8; ++j)
      acc[j] = fmaf(a0, w0[j], fmaf(a1, w1[j], fmaf(a2, w2[j], fmaf(a3, w3[j], acc[j]))));
  }

  size_t o = ((size_t)b * Tout + t0 + lane) * 64 + co0;
  #pragma unroll
  for (int q = 0; q < 2; ++q) {
    float4 rr;
    rr.x = fmaxf(acc[4*q+0] + bias[co0 + 4*q+0], 0.f);
    rr.y = fmaxf(acc[4*q+1] + bias[co0 + 4*q+1], 0.f);
    rr.z = fmaxf(acc[4*q+2] + bias[co0 + 4*q+2], 0.f);
    rr.w = fmaxf(acc[4*q+3] + bias[co0 + 4*q+3], 0.f);
    *(float4*)&y[o + 4 * q] = rr;
  }
}

// ---------------- up: conv_transpose K=4 stride2, 64->64, relu, TPL=2 -----
// 128 u per block (down2's staging geometry). Per lane u = u0 + 2*lane + i.
// y[2u]=relu(b + w0^T x[u-1] + w2^T x[u]); y[2u+1]=relu(b + w1^T x[u] + w3^T x[u+1])
// grid (Tin/128, 4). Per-output fmaf chain identical to r10 (bit-exact).
__global__ __launch_bounds__(512, 8) void up_kernel(
    const float* __restrict__ x, const float* __restrict__ w,
    const float* __restrict__ bias, float* __restrict__ y, int Tin)
{
  constexpr int XT = 130, XS = 144;          // swizzle-safe stride
  __shared__ float xs[64 * XS];
  const int tid  = threadIdx.x;
  const int lane = tid & 63;
  const int b    = blockIdx.y;
  const int u0   = blockIdx.x * 128;
  const int Tout = Tin << 1;
  const int wv   = __builtin_amdgcn_readfirstlane(tid >> 6);
  const int co0  = __builtin_amdgcn_readfirstlane(wv * 8);

  const float* xb = x + (size_t)b * Tin * 64;
  for (int e = tid; e < 16 * XT; e += 512) { // stage x[u0-1 .. u0+129)
    int ul = e >> 4, cq = (e & 15) * 4;
    int cs = ul ^ (((cq >> 2) & 7) << 1);
    int gu = u0 - 1 + ul;
    float4 v = make_float4(0.f, 0.f, 0.f, 0.f);
    if ((unsigned)gu < (unsigned)Tin) v = *(const float4*)&xb[(size_t)gu * 64 + cq];
    xs[(cq + 0) * XS + cs] = v.x;
    xs[(cq + 1) * XS + cs] = v.y;
    xs[(cq + 2) * XS + cs] = v.z;
    xs[(cq + 3) * XS + cs] = v.w;
  }
  __syncthreads();

  const int tb = 2 * lane;                   // xs col of x[u-1] for i=0
  float acce[2][8] = {}, acco[2][8] = {};
  const float* wb = w + co0;
  for (int ci = 0; ci < 64; ++ci) {
    const int swz = ((ci >> 2) & 7) << 1;
    const float* xr = xs + ci * XS;
    float2 v0 = *(const float2*)&xr[(tb) ^ swz];      // x[u-1], x[u]
    float2 v1 = *(const float2*)&xr[(tb + 2) ^ swz];  // x[u+1], x[u+2]
    float a0 = v0.x, a1 = v0.y, a2 = v1.x, a3 = v1.y;
    const float* w0 = wb + (0 * 64 + ci) * 64;
    const float* w1 = wb + (1 * 64 + ci) * 64;
    const float* w2 = wb + (2 * 64 + ci) * 64;
    const float* w3 = wb + (3 * 64 + ci) * 64;
    #pragma unroll
    for (int j = 0; j < 8; ++j) {
      float c0 = w0[j], c1 = w1[j], c2 = w2[j], c3 = w3[j];
      acce[0][j] = fmaf(a0, c0, fmaf(a1, c2, acce[0][j]));
      acco[0][j] = fmaf(a1, c1, fmaf(a2, c3, acco[0][j]));
      acce[1][j] = fmaf(a1, c0, fmaf(a2, c2, acce[1][j]));
      acco[1][j] = fmaf(a2, c1, fmaf(a3, c3, acco[1][j]));
    }
  }

  #pragma unroll
  for (int i = 0; i < 2; ++i) {
    const int u = u0 + tb + i;
    size_t oe = ((size_t)b * Tout + 2 * u) * 64 + co0;
    size_t oo = oe + 64;
    #pragma unroll
    for (int q = 0; q < 2; ++q) {
      float4 re, ro;
      re.x = fmaxf(acce[i][4*q+0] + bias[co0 + 4*q+0], 0.f);
      re.y = fmaxf(acce[i][4*q+1] + bias[co0 + 4*q+1], 0.f);
      re.z = fmaxf(acce[i][4*q+2] + bias[co0 + 4*q+2], 0.f);
      re.w = fmaxf(acce[i][4*q+3] + bias[co0 + 4*q+3], 0.f);
      ro.x = fmaxf(acco[i][4*q+0] + bias[co0 + 4*q+0], 0.f);
      ro.y = fmaxf(acco[i][4*q+1] + bias[co0 + 4*q+1], 0.f);
      ro.z = fmaxf(acco[i][4*q+2] + bias[co0 + 4*q+2], 0.f);
      ro.w = fmaxf(acco[i][4*q+3] + bias[co0 + 4*q+3], 0.f);
      *(float4*)&y[oe + 4 * q] = re;
      *(float4*)&y[oo + 4 * q] = ro;
    }
  }
}

// ---------------- proj: K=3 dil1, 64->1, linear ---------------------------
__global__ __launch_bounds__(256) void proj_kernel(
    const float* __restrict__ x, const float* __restrict__ w,
    const float* __restrict__ bias, float* __restrict__ out)
{
  const int lane = threadIdx.x & 63;
  const int wid  = (blockIdx.x * 256 + threadIdx.x) >> 6;  // 4096 waves
  const float w0 = w[lane], w1 = w[64 + lane], w2 = w[128 + lane];
  const float bb = bias[0];
  size_t base = (size_t)wid * 64;
  for (int i = 0; i < 64; ++i) {
    size_t tau = base + i;
    int b = (int)(tau >> 16);
    int t = (int)(tau & 65535);
    const float* xb = x + ((size_t)b * 65536) * 64;
    float pm = (t > 0)     ? xb[(size_t)(t - 1) * 64 + lane] : 0.f;
    float pc =               xb[(size_t)t * 64 + lane];
    float pp = (t < 65535) ? xb[(size_t)(t + 1) * 64 + lane] : 0.f;
    float s = pm * w0 + pc * w1 + pp * w2;
    #pragma unroll
    for (int off = 32; off; off >>= 1) s += __shfl_down(s, off);
    if (lane == 0) out[tau] = s + bb;
  }
}

// ---------------- nz: per-token sum of squares ----------------------------
__global__ __launch_bounds__(256) void nz_kernel(
    const float* __restrict__ ze, float* __restrict__ nz)
{
  int lane = threadIdx.x & 63;
  int tok  = (blockIdx.x * 256 + threadIdx.x) >> 6;
  float v = ze[(size_t)tok * 64 + lane];
  float s = v * v;
  #pragma unroll
  for (int off = 32; off; off >>= 1) s += __shfl_down(s, off);
  if (lane == 0) nz[tok] = s;
}

// ---------------- ne: per-entry codebook norm (512 entries, once) ---------
__global__ __launch_bounds__(256) void ne_kernel(
    const float* __restrict__ cb, float* __restrict__ ne)
{
  int c = blockIdx.x * 256 + threadIdx.x;   // grid 2 -> 512 entries
  const float4* p = (const float4*)(cb + (size_t)c * 64);
  float s = 0.f;
  #pragma unroll
  for (int q = 0; q < 16; ++q) {
    float4 v = p[q];
    s += v.x * v.x + v.y * v.y + v.z * v.z + v.w * v.w;
  }
  ne[c] = s;
}

// ---------------- vq_dots: register-blocked GEMM --------------------------
__global__ __launch_bounds__(256) void vq_dots_kernel(
    const float* __restrict__ ze, const float* __restrict__ cb,
    const float* __restrict__ nzbuf, const float* __restrict__ nebuf,
    float* __restrict__ sim_out, float2* __restrict__ pmin)
{
  constexpr int ZS = 68, CS = 132;
  __shared__ float zt[64 * ZS];              // [d][tok]   17.4 KB
  __shared__ float ct[64 * CS];              // [d][ent]   33.8 KB
  const int tid = threadIdx.x;
  const int tx  = tid & 15;                  // entry group (8 entries)
  const int ty  = tid >> 4;                  // token group (4 tokens)
  const int bx  = blockIdx.x, by = blockIdx.y;

  {                                          // stage z tile (transpose, swz)
    const float* zb = ze + (size_t)bx * 64 * 64;
    #pragma unroll
    for (int it = 0; it < 4; ++it) {
      int e = tid + it * 256;
      int tl = e >> 4, cq = (e & 15) * 4;
      int cs = tl ^ (((cq >> 2) & 7) << 2);
      float4 v = *(const float4*)&zb[tl * 64 + cq];
      zt[(cq + 0) * ZS + cs] = v.x;
      zt[(cq + 1) * ZS + cs] = v.y;
      zt[(cq + 2) * ZS + cs] = v.z;
      zt[(cq + 3) * ZS + cs] = v.w;
    }
    const float* cbb = cb + (size_t)by * 128 * 64;
    #pragma unroll
    for (int it = 0; it < 8; ++it) {
      int e = tid + it * 256;
      int el = e >> 4, cq = (e & 15) * 4;
      int cs = el ^ (((cq >> 2) & 7) << 2);
      float4 v = *(const float4*)&cbb[el * 64 + cq];
      ct[(cq + 0) * CS + cs] = v.x;
      ct[(cq + 1) * CS + cs] = v.y;
      ct[(cq + 2) * CS + cs] = v.z;
      ct[(cq + 3) * CS + cs] = v.w;
    }
  }
  __syncthreads();

  float acc[4][8] = {};
  #pragma unroll 4
  for (int k = 0; k < 64; ++k) {
    const int swz = ((k >> 2) & 7) << 2;
    float4 zv = *(const float4*)&zt[k * ZS + ((ty * 4) ^ swz)];
    float4 c0 = *(const float4*)&ct[k * CS + ((tx * 8) ^ swz)];
    float4 c1 = *(const float4*)&ct[k * CS + ((tx * 8 + 4) ^ swz)];
    float zr[4] = {zv.x, zv.y, zv.z, zv.w};
    float cr[8] = {c0.x, c0.y, c0.z, c0.w, c1.x, c1.y, c1.z, c1.w};
    #pragma unroll
    for (int i = 0; i < 4; ++i)
      #pragma unroll
      for (int j = 0; j < 8; ++j)
        acc[i][j] = fmaf(zr[i], cr[j], acc[i][j]);
  }

  // epilogue: dist, sim, argmin partials
  float4 nzq = *(const float4*)&nzbuf[bx * 64 + ty * 4];
  float nzv[4] = {nzq.x, nzq.y, nzq.z, nzq.w};
  float4 ne0  = *(const float4*)&nebuf[by * 128 + tx * 8];
  float4 ne1  = *(const float4*)&nebuf[by * 128 + tx * 8 + 4];
  float nev[8]  = {ne0.x, ne0.y, ne0.z, ne0.w, ne1.x, ne1.y, ne1.z, ne1.w};
  float rsne[8];
  #pragma unroll
  for (int j = 0; j < 8; ++j) rsne[j] = 1.f / sqrtf(nev[j]);
  const int ent0 = by * 128 + tx * 8;

  #pragma unroll
  for (int i = 0; i < 4; ++i) {
    const int tok = bx * 64 + ty * 4 + i;
    const float rsnz = 1.f / sqrtf(nzv[i]);
    float dist[8], simv[8];
    #pragma unroll
    for (int j = 0; j < 8; ++j) {
      dist[j] = (-2.f * acc[i][j] + nzv[i]) + nev[j];
      simv[j] = acc[i][j] * rsnz * rsne[j];
    }
    float* so = sim_out + (size_t)tok * 512 + ent0;
    *(float4*)&so[0] = make_float4(simv[0], simv[1], simv[2], simv[3]);
    *(float4*)&so[4] = make_float4(simv[4], simv[5], simv[6], simv[7]);

    float md = dist[0]; int mi = ent0;       // ascending strict < -> lowest j
    #pragma unroll
    for (int j = 1; j < 8; ++j)
      if (dist[j] < md) { md = dist[j]; mi = ent0 + j; }
    #pragma unroll
    for (int off = 1; off < 16; off <<= 1) { // reduce across 16-lane tx group
      float od = __shfl_xor(md, off);
      int   oi = __shfl_xor(mi, off);
      if (od < md || (od == md && oi < mi)) { md = od; mi = oi; }
    }
    if (tx == 0) pmin[tok * 4 + by] = make_float2(md, (float)mi);
  }
}

// ---------------- vq_finish: cross-partial argmin, z_q, ids, loss ---------
__global__ __launch_bounds__(256) void vq_finish_kernel(
    const float* __restrict__ ze, const float* __restrict__ cb,
    const float2* __restrict__ pmin, float* __restrict__ zq,
    float* __restrict__ ids_out, float* __restrict__ blocksum)
{
  const int tid = threadIdx.x;
  const int lane = tid & 63, wvid = tid >> 6;
  float lloss = 0.f;
  for (int it = 0; it < 16; ++it) {
    const int tok = blockIdx.x * 64 + wvid * 16 + it;
    float bd = 1e30f; int bi = 0;
    #pragma unroll
    for (int p = 0; p < 4; ++p) {            // 4 entry-tile partials, ascending
      float2 pr = pmin[tok * 4 + p];
      float d = pr.x; int i = (int)pr.y;
      if (d < bd || (d == bd && i < bi)) { bd = d; bi = i; }
    }
    float zev = ze[(size_t)tok * 64 + lane];
    float cv  = cb[(size_t)bi * 64 + lane];
    float df = zev - cv;
    float s = df * df;
    #pragma unroll
    for (int off = 32; off; off >>= 1) s += __shfl_down(s, off);
    zq[(size_t)tok * 64 + lane] = cv;
    if (lane == 0) { ids_out[tok] = (float)bi; lloss += sqrtf(s); }
  }
  __shared__ float ls[4];
  if (lane == 0) ls[wvid] = lloss;
  __syncthreads();
  if (tid == 0) blocksum[blockIdx.x] = ls[0] + ls[1] + ls[2] + ls[3];
}

__global__ void loss_fin_kernel(const float* __restrict__ blocksum,
                                float* __restrict__ out)
{
  const int lane = threadIdx.x;  // 64 threads
  float s = 0.f;
  for (int i = lane; i < 512; i += 64) s += blocksum[i];
  #pragma unroll
  for (int off = 32; off; off >>= 1) s += __shfl_down(s, off);
  if (lane == 0) out[0] = 1.25f * s / 32768.f;
}

// ---------------------------------------------------------------------------
#define LAUNCH_CONV3(DILV, RESV, XP, WP, BP, RP, YP)                           \
  do {                                                                         \
    if (T >= 16384)                                                            \
      conv3_kernel<DILV, RESV, 128><<<dim3(T / 128, 4), 512, 0, stream>>>(     \
          XP, WP, BP, RP, YP, T);                                              \
    else                                                                       \
      conv3_kernel<DILV, RESV, 64><<<dim3(T / 64, 4), 512, 0, stream>>>(       \
          XP, WP, BP, RP, YP, T);                                              \
  } while (0)

extern "C" void kernel_launch(void* const* d_in, const int* in_sizes, int n_in,
                              void* d_out, int out_size, void* d_ws, size_t ws_size,
                              hipStream_t stream)
{
  const float* x       = (const float*)d_in[0];
  const float* w_down0 = (const float*)d_in[1];
  const float* b_down0 = (const float*)d_in[2];
  const float* w_down  = (const float*)d_in[3];
  const float* b_down  = (const float*)d_in[4];
  const float* w_res_e = (const float*)d_in[5];
  const float* b_res_e = (const float*)d_in[6];
  const float* cb      = (const float*)d_in[7];
  const float* w_res_d = (const float*)d_in[8];
  const float* b_res_d = (const float*)d_in[9];
  const float* w_up    = (const float*)d_in[10];
  const float* b_up    = (const float*)d_in[11];
  const float* w_proj  = (const float*)d_in[12];
  const float* b_proj  = (const float*)d_in[13];

  float* out = (float*)d_out;
  const size_t BUF = (size_t)4 * 65536 * 64;
  float*  bufA     = (float*)d_ws;
  float*  bufB     = bufA + BUF;
  float*  nzbuf    = bufB + BUF;
  float*  nebuf    = nzbuf + 32768;
  float2* pmin     = (float2*)(nebuf + 512);
  float*  blocksum = (float*)(pmin + 32768 * 4);

  float* h = bufA;
  float* tmp = bufB;

  // ---- encoder ----
  down0_kernel<<<32768, 256, 0, stream>>>(x, w_down0, b_down0, h);
  int T = 32768;
  for (int blk = 0; blk < 3; ++blk) {
    if (blk > 0) {
      down2_kernel<<<dim3(T / 2 / 64, 4), 512, 0, stream>>>(
          h, w_down + (size_t)(blk - 1) * 4 * 64 * 64, b_down + (blk - 1) * 64, tmp, T);
      T >>= 1;
      float* s = h; h = tmp; tmp = s;
    }
    for (int r = 0; r < 4; ++r) {
      const float* w0p = w_res_e + (((size_t)blk * 4 + r) * 2 + 0) * 3 * 64 * 64;
      const float* w1p = w_res_e + (((size_t)blk * 4 + r) * 2 + 1) * 3 * 64 * 64;
      const float* b0p = b_res_e + (((size_t)blk * 4 + r) * 2 + 0) * 64;
      const float* b1p = b_res_e + (((size_t)blk * 4 + r) * 2 + 1) * 64;
      LAUNCH_CONV3(3, false, h, w0p, b0p, nullptr, tmp);
      LAUNCH_CONV3(1, true,  tmp, w1p, b1p, h, h);
    }
  }

  // ---- VQ (T == 8192, z_e in h; 32768 tokens) ----
  nz_kernel<<<8192, 256, 0, stream>>>(h, nzbuf);
  ne_kernel<<<2, 256, 0, stream>>>(cb, nebuf);
  vq_dots_kernel<<<dim3(512, 4), 256, 0, stream>>>(h, cb, nzbuf, nebuf, out + OFF_SIM, pmin);
  vq_finish_kernel<<<512, 256, 0, stream>>>(h, cb, pmin, tmp, out + OFF_IDS, blocksum);
  loss_fin_kernel<<<1, 64, 0, stream>>>(blocksum, out + OFF_LOSS);
  { float* s = h; h = tmp; tmp = s; }  // h = z_q

  // ---- decoder ----
  for (int blk = 0; blk < 3; ++blk) {
    for (int r = 0; r < 4; ++r) {
      const float* w0p = w_res_d + (((size_t)blk * 4 + r) * 2 + 0) * 3 * 64 * 64;
      const float* w1p = w_res_d + (((size_t)blk * 4 + r) * 2 + 1) * 3 * 64 * 64;
      const float* b0p = b_res_d + (((size_t)blk * 4 + r) * 2 + 0) * 64;
      const float* b1p = b_res_d + (((size_t)blk * 4 + r) * 2 + 1) * 64;
      LAUNCH_CONV3(1, false, h, w0p, b0p, nullptr, tmp);
      LAUNCH_CONV3(3, true,  tmp, w1p, b1p, h, h);
    }
    up_kernel<<<dim3(T / 128, 4), 512, 0, stream>>>(
        h, w_up + (size_t)blk * 4 * 64 * 64, b_up + blk * 64, tmp, T);
    T <<= 1;
    float* s = h; h = tmp; tmp = s;
  }

  // ---- final projection (T == 65536) ----
  proj_kernel<<<1024, 256, 0, stream>>>(h, w_proj, b_proj, out);
}